// Round 12
// baseline (1968.115 us; speedup 1.0000x reference)
//
#include <hip/hip_runtime.h>

typedef __attribute__((ext_vector_type(8))) short short8;
typedef __attribute__((ext_vector_type(4))) float f32x4;

static constexpr int BN    = 512;
static constexpr int ID    = 1024;
static constexpr int HDm   = 2048;
static constexpr int LD    = 1000;
static constexpr int TMAXc = 32;
static constexpr float ALPHAc = 0.05f;

// ---------------- bf16 split helpers (x ~= hi + lo, each bf16) ----------------
__device__ __forceinline__ unsigned short f2bf(float x) {
    unsigned u = __float_as_uint(x);
    u += 0x7fffu + ((u >> 16) & 1u);           // RNE
    return (unsigned short)(u >> 16);
}
__device__ __forceinline__ float bf2f(unsigned short h) {
    return __uint_as_float(((unsigned)h) << 16);
}
__device__ __forceinline__ void split2(float x, unsigned short& hi, unsigned short& lo) {
    hi = f2bf(x);
    lo = f2bf(x - bf2f(hi));
}

// ---------------------------------------------------------------------------
// 64x32 tile, K-chunk 128, 1024 threads: 8 fragments (4 frow x 2 fcol) x
// 2-way K-split. 3-deep register prefetch, split-bf16 3-term MFMA.
// LDS: Ah 16K | Al 16K | Bh 8K | Bl 8K = 48 KB. Swizzle: byte ^= (row&15)<<4.
// ---------------------------------------------------------------------------
template<bool SPLITA>
__device__ __forceinline__ void tile64x32(
    const float* __restrict__ Af,
    const unsigned short* __restrict__ Ahi, const unsigned short* __restrict__ Alo,
    int lda, int row0,
    const unsigned short* __restrict__ BThi, const unsigned short* __restrict__ BTlo,
    int ldk, int col0, int K, char* lds, f32x4& acc, int& s_out, int& p_out)
{
    char* Ah = lds;
    char* Al = lds + 16384;
    char* Bh = lds + 32768;
    char* Bl = lds + 40960;
    const int t = threadIdx.x, lane = t & 63, w = t >> 6;
    const int s = w & 7, p = w >> 3;
    s_out = s; p_out = p;
    f32x4 z = {0.f, 0.f, 0.f, 0.f};
    acc = z;

    const int ar = t >> 4, ac = (t & 15) << 3;     // A: 64 rows x 128, 8 elems/stream
    const int br = t >> 5, bc = (t & 31) << 2;     // B: 32 rows x 128, 4 elems/stream
    const int asb = (ar * 256 + ac * 2) ^ ((ar & 15) << 4);
    const int bsb = (br * 256 + bc * 2) ^ ((br & 15) << 4);
    const float* Ap = SPLITA ? (Af + (size_t)(row0 + ar) * lda + ac) : nullptr;
    const unsigned short* Ahp = SPLITA ? nullptr : (Ahi + (size_t)(row0 + ar) * lda + ac);
    const unsigned short* Alp = SPLITA ? nullptr : (Alo + (size_t)(row0 + ar) * lda + ac);
    const unsigned short* Bhp = BThi + (size_t)(col0 + br) * ldk + bc;
    const unsigned short* Blp = BTlo + (size_t)(col0 + br) * ldk + bc;

    const int frow = s >> 1, fcol = s & 1;
    const int arow = frow * 16 + (lane & 15);
    const int colr = fcol * 16 + (lane & 15);
    const int ab0 = arow * 256, bb0 = colr * 256;
    const int axor = (arow & 15) << 4, bxor = (colr & 15) << 4;
    const int kwin = p * 128 + ((lane >> 4) << 4);

    // 3-deep prefetch pipeline (K >= 384 always here)
    float4 af0a, af0b, af1a, af1b, af2a, af2b;
    uint4 ah0, al0, ah1, al1, ah2, al2;
    if constexpr (SPLITA) {
        af0a = *(const float4*)(Ap);       af0b = *(const float4*)(Ap + 4);
        af1a = *(const float4*)(Ap + 128); af1b = *(const float4*)(Ap + 132);
        af2a = *(const float4*)(Ap + 256); af2b = *(const float4*)(Ap + 260);
    } else {
        ah0 = *(const uint4*)(Ahp);       al0 = *(const uint4*)(Alp);
        ah1 = *(const uint4*)(Ahp + 128); al1 = *(const uint4*)(Alp + 128);
        ah2 = *(const uint4*)(Ahp + 256); al2 = *(const uint4*)(Alp + 256);
    }
    uint2 bh0 = *(const uint2*)(Bhp),       bl0 = *(const uint2*)(Blp);
    uint2 bh1 = *(const uint2*)(Bhp + 128), bl1 = *(const uint2*)(Blp + 128);
    uint2 bh2 = *(const uint2*)(Bhp + 256), bl2 = *(const uint2*)(Blp + 256);

    for (int k0 = 0; k0 < K; k0 += 128) {
        uint4 awh, awl;
        if constexpr (SPLITA) {
            unsigned short h[8], l[8];
            const float vv[8] = {af0a.x, af0a.y, af0a.z, af0a.w,
                                 af0b.x, af0b.y, af0b.z, af0b.w};
#pragma unroll
            for (int i = 0; i < 8; ++i) split2(vv[i], h[i], l[i]);
            awh = make_uint4((unsigned)h[0] | ((unsigned)h[1] << 16),
                             (unsigned)h[2] | ((unsigned)h[3] << 16),
                             (unsigned)h[4] | ((unsigned)h[5] << 16),
                             (unsigned)h[6] | ((unsigned)h[7] << 16));
            awl = make_uint4((unsigned)l[0] | ((unsigned)l[1] << 16),
                             (unsigned)l[2] | ((unsigned)l[3] << 16),
                             (unsigned)l[4] | ((unsigned)l[5] << 16),
                             (unsigned)l[6] | ((unsigned)l[7] << 16));
        } else { awh = ah0; awl = al0; }
        const uint2 bwh = bh0, bwl = bl0;
        __syncthreads();                            // prior LDS readers done
        *(uint4*)(Ah + asb) = awh;
        *(uint4*)(Al + asb) = awl;
        *(uint2*)(Bh + bsb) = bwh;
        *(uint2*)(Bl + bsb) = bwl;
        if constexpr (SPLITA) { af0a = af1a; af0b = af1b; af1a = af2a; af1b = af2b; }
        else { ah0 = ah1; al0 = al1; ah1 = ah2; al1 = al2; }
        bh0 = bh1; bl0 = bl1; bh1 = bh2; bl1 = bl2;
        if (k0 + 384 < K) {
            if constexpr (SPLITA) {
                af2a = *(const float4*)(Ap + k0 + 384);
                af2b = *(const float4*)(Ap + k0 + 388);
            } else {
                ah2 = *(const uint4*)(Ahp + k0 + 384);
                al2 = *(const uint4*)(Alp + k0 + 384);
            }
            bh2 = *(const uint2*)(Bhp + k0 + 384);
            bl2 = *(const uint2*)(Blp + k0 + 384);
        }
        __syncthreads();
#pragma unroll
        for (int ks = 0; ks < 2; ++ks) {
            const int kb = kwin + ks * 64;
            short8 bh = *(const short8*)(Bh + ((bb0 + kb) ^ bxor));
            short8 bl = *(const short8*)(Bl + ((bb0 + kb) ^ bxor));
            short8 ah = *(const short8*)(Ah + ((ab0 + kb) ^ axor));
            short8 al = *(const short8*)(Al + ((ab0 + kb) ^ axor));
            acc = __builtin_amdgcn_mfma_f32_16x16x32_bf16(ah, bh, acc, 0, 0, 0);
            acc = __builtin_amdgcn_mfma_f32_16x16x32_bf16(al, bh, acc, 0, 0, 0);
            acc = __builtin_amdgcn_mfma_f32_16x16x32_bf16(ah, bl, acc, 0, 0, 0);
        }
    }
}

// ---------------------------------------------------------------------------
// 32x32 tile, K-chunk 128, 1024 threads: 4 fragments x 4-way K-split (p=w>>2).
// LDS: Ah 8K | Al 8K | Bh 8K | Bl 8K = 32 KB (+12 KB reduce region after).
// ---------------------------------------------------------------------------
__device__ __forceinline__ void tile32x32(
    const unsigned short* __restrict__ Ahi, const unsigned short* __restrict__ Alo, int row0,
    const unsigned short* __restrict__ BThi, const unsigned short* __restrict__ BTlo,
    int col0, char* lds, f32x4& acc, int& s_out, int& p_out)
{
    char* Ah = lds;
    char* Al = lds + 8192;
    char* Bh = lds + 16384;
    char* Bl = lds + 24576;
    const int t = threadIdx.x, lane = t & 63, w = t >> 6;
    const int s = w & 3, p = w >> 2;
    s_out = s; p_out = p;
    f32x4 z = {0.f, 0.f, 0.f, 0.f};
    acc = z;

    const int ar = t >> 5, ac = (t & 31) << 2;     // 32 rows x 128, 4 elems/stream
    const int asb = (ar * 256 + ac * 2) ^ ((ar & 15) << 4);
    const unsigned short* Ahp = Ahi + (size_t)(row0 + ar) * HDm + ac;
    const unsigned short* Alp = Alo + (size_t)(row0 + ar) * HDm + ac;
    const unsigned short* Bhp = BThi + (size_t)(col0 + ar) * HDm + ac;
    const unsigned short* Blp = BTlo + (size_t)(col0 + ar) * HDm + ac;

    const int frow = s >> 1, fcol = s & 1;
    const int arow = frow * 16 + (lane & 15);
    const int colr = fcol * 16 + (lane & 15);
    const int ab0 = arow * 256, bb0 = colr * 256;
    const int axor = (arow & 15) << 4, bxor = (colr & 15) << 4;
    const int kwin = p * 64 + ((lane >> 4) << 4);

    uint2 ah0 = *(const uint2*)(Ahp),       al0 = *(const uint2*)(Alp);
    uint2 bh0 = *(const uint2*)(Bhp),       bl0 = *(const uint2*)(Blp);
    uint2 ah1 = *(const uint2*)(Ahp + 128), al1 = *(const uint2*)(Alp + 128);
    uint2 bh1 = *(const uint2*)(Bhp + 128), bl1 = *(const uint2*)(Blp + 128);

    for (int k0 = 0; k0 < HDm; k0 += 128) {
        const uint2 awh = ah0, awl = al0, bwh = bh0, bwl = bl0;
        __syncthreads();
        *(uint2*)(Ah + asb) = awh;
        *(uint2*)(Al + asb) = awl;
        *(uint2*)(Bh + asb) = bwh;
        *(uint2*)(Bl + asb) = bwl;
        ah0 = ah1; al0 = al1; bh0 = bh1; bl0 = bl1;
        if (k0 + 256 < HDm) {
            ah1 = *(const uint2*)(Ahp + k0 + 256);
            al1 = *(const uint2*)(Alp + k0 + 256);
            bh1 = *(const uint2*)(Bhp + k0 + 256);
            bl1 = *(const uint2*)(Blp + k0 + 256);
        }
        __syncthreads();
        const int kb = kwin;
        short8 bh = *(const short8*)(Bh + ((bb0 + kb) ^ bxor));
        short8 bl = *(const short8*)(Bl + ((bb0 + kb) ^ bxor));
        short8 ah = *(const short8*)(Ah + ((ab0 + kb) ^ axor));
        short8 al = *(const short8*)(Al + ((ab0 + kb) ^ axor));
        acc = __builtin_amdgcn_mfma_f32_16x16x32_bf16(ah, bh, acc, 0, 0, 0);
        acc = __builtin_amdgcn_mfma_f32_16x16x32_bf16(al, bh, acc, 0, 0, 0);
        acc = __builtin_amdgcn_mfma_f32_16x16x32_bf16(ah, bl, acc, 0, 0, 0);
    }
}

// ---------------------------------------------------------------------------
// Prep kernels
// ---------------------------------------------------------------------------
__global__ void k_init(int* active, int* cnt, float* scal,
                       float* margS, float* drift, int* fresh)
{
    int i = blockIdx.x * blockDim.x + threadIdx.x;
    if (i < 2 * BN) {
        active[i] = 1;
        margS[i] = 3.4e38f;
        drift[i] = 0.f;
        fresh[i] = 1;
    }
    if (i < 16) cnt[i] = 64;
    if (i < 8) scal[i] = 0.f;
}

__global__ __launch_bounds__(256) void k_colsum_wh(const float* __restrict__ RH,
                                                   const float* __restrict__ MH,
                                                   float* __restrict__ part)
{
    const int colTile = blockIdx.x >> 3, rs = blockIdx.x & 7;
    const int col = colTile * 64 + (threadIdx.x & 63);
    const int rq = threadIdx.x >> 6;
    const int r0 = rs * 256;
    float s = 0.f;
    for (int i = r0 + rq; i < r0 + 256; i += 4)
        s += fabsf(RH[(size_t)i * HDm + col] * MH[(size_t)i * HDm + col]);
    __shared__ float red[4][64];
    red[rq][threadIdx.x & 63] = s;
    __syncthreads();
    if (threadIdx.x < 64)
        part[(size_t)rs * HDm + col] = red[0][threadIdx.x] + red[1][threadIdx.x] +
                                       red[2][threadIdx.x] + red[3][threadIdx.x];
}

__global__ __launch_bounds__(256) void k_colsum_whl(const float* __restrict__ RHL,
                                                    const float* __restrict__ MHL,
                                                    float* __restrict__ part)
{
    const int colTile = blockIdx.x >> 3, rs = blockIdx.x & 7;
    const int col = colTile * 64 + (threadIdx.x & 63);
    const int rq = threadIdx.x >> 6;
    const int r0 = rs * 256;
    float s = 0.f;
    if (col < LD) {
        for (int i = r0 + rq; i < r0 + 256; i += 4)
            s += fabsf(RHL[(size_t)i * LD + col] * MHL[(size_t)i * LD + col]);
    }
    __shared__ float red[4][64];
    red[rq][threadIdx.x & 63] = s;
    __syncthreads();
    if (threadIdx.x < 64)
        part[(size_t)rs * 1024 + col] = red[0][threadIdx.x] + red[1][threadIdx.x] +
                                        red[2][threadIdx.x] + red[3][threadIdx.x];
}

__global__ __launch_bounds__(1024) void k_scalars(const float* __restrict__ part_wh,
                                                  const float* __restrict__ part_whl,
                                                  float* scal)
{
    float m1 = 0.f, m2 = 0.f;
    for (int c = threadIdx.x; c < HDm; c += 1024) {
        float s = 0.f;
#pragma unroll
        for (int k = 0; k < 8; ++k) s += part_wh[(size_t)k * HDm + c];
        m1 = fmaxf(m1, s);
    }
    {
        const int c = threadIdx.x;
        if (c < 1024) {
            float s = 0.f;
#pragma unroll
            for (int k = 0; k < 8; ++k) s += part_whl[(size_t)k * 1024 + c];
            m2 = fmaxf(m2, s);
        }
    }
#pragma unroll
    for (int off = 1; off < 64; off <<= 1) {
        m1 = fmaxf(m1, __shfl_xor(m1, off));
        m2 = fmaxf(m2, __shfl_xor(m2, off));
    }
    __shared__ float r1[16], r2[16];
    if ((threadIdx.x & 63) == 0) { r1[threadIdx.x >> 6] = m1; r2[threadIdx.x >> 6] = m2; }
    __syncthreads();
    if (threadIdx.x == 0) {
        float a = 0.f, b = 0.f;
#pragma unroll
        for (int i = 0; i < 16; ++i) { a = fmaxf(a, r1[i]); b = fmaxf(b, r2[i]); }
        scal[2] = 0.95f / fmaxf(a, 1e-8f);
        scal[3] = b * 19.f;
    }
}

// Transposed split:  O{hi,lo}[c][r] = split(R[r][c] * M[r][c] * s)
__global__ __launch_bounds__(256) void k_wsplit(
    const float* __restrict__ R, const float* __restrict__ M,
    unsigned short* __restrict__ Ohi, unsigned short* __restrict__ Olo,
    int NR, int NC, int NCp, const float* __restrict__ scal, int scidx)
{
    __shared__ float T[64][65];
    const int nct = NCp >> 6;
    const int c0 = (blockIdx.x % nct) << 6;
    const int r0 = (blockIdx.x / nct) << 6;
    const float s = (scidx >= 0) ? scal[scidx] : 1.f;
    const int t = threadIdx.x;
    const int ir = t >> 2, ics = (t & 3) << 4;
#pragma unroll
    for (int i = 0; i < 16; ++i) {
        const int c = c0 + ics + i;
        float v = 0.f;
        if (c < NC) {
            const size_t idx = (size_t)(r0 + ir) * NC + c;
            v = R[idx] * M[idx] * s;
        }
        T[ir][ics + i] = v;
    }
    __syncthreads();
    const int oc = t >> 2, ors = (t & 3) << 4;
    unsigned short hb[16], lb[16];
#pragma unroll
    for (int i = 0; i < 16; ++i) split2(T[ors + i][oc], hb[i], lb[i]);
    const size_t base = (size_t)(c0 + oc) * NR + r0 + ors;
    uint4 v;
    v.x = hb[0] | ((unsigned)hb[1] << 16);  v.y = hb[2] | ((unsigned)hb[3] << 16);
    v.z = hb[4] | ((unsigned)hb[5] << 16);  v.w = hb[6] | ((unsigned)hb[7] << 16);
    *(uint4*)(Ohi + base) = v;
    v.x = hb[8] | ((unsigned)hb[9] << 16);  v.y = hb[10] | ((unsigned)hb[11] << 16);
    v.z = hb[12] | ((unsigned)hb[13] << 16); v.w = hb[14] | ((unsigned)hb[15] << 16);
    *(uint4*)(Ohi + base + 8) = v;
    v.x = lb[0] | ((unsigned)lb[1] << 16);  v.y = lb[2] | ((unsigned)lb[3] << 16);
    v.z = lb[4] | ((unsigned)lb[5] << 16);  v.w = lb[6] | ((unsigned)lb[7] << 16);
    *(uint4*)(Olo + base) = v;
    v.x = lb[8] | ((unsigned)lb[9] << 16);  v.y = lb[10] | ((unsigned)lb[11] << 16);
    v.z = lb[12] | ((unsigned)lb[13] << 16); v.w = lb[14] | ((unsigned)lb[15] << 16);
    *(uint4*)(Olo + base + 8) = v;
}

// drive = x @ W_IH + BH   (512 blocks = 8 x 64 tiles of 64x32, K=1024)
__global__ __launch_bounds__(1024, 8) void k_drive_mfma(
    const float* __restrict__ x,
    const unsigned short* __restrict__ WIHThi, const unsigned short* __restrict__ WIHTlo,
    const float* __restrict__ BH, float* __restrict__ drive)
{
    __shared__ char lds[49152];
    f32x4 acc;
    int s, p;
    const int row0 = (blockIdx.x >> 6) * 64, col0 = (blockIdx.x & 63) * 32;
    tile64x32<true>(x, nullptr, nullptr, ID, row0, WIHThi, WIHTlo, ID, col0, ID,
                    lds, acc, s, p);
    const int lane = threadIdx.x & 63;
    __syncthreads();
    f32x4* red = (f32x4*)lds;
    if (p == 1) red[s * 64 + lane] = acc;
    __syncthreads();
    if (p == 0) {
        f32x4 o = red[s * 64 + lane];
        acc += o;
        const int frow = s >> 1, fcol = s & 1;
        const int gc = col0 + fcol * 16 + (lane & 15);
        const int gr0 = row0 + frow * 16 + ((lane >> 4) << 2);
        const float bh = BH[gc];
#pragma unroll
        for (int r = 0; r < 4; ++r)
            drive[(size_t)(gr0 + r) * HDm + gc] = acc[r] + bh;
    }
}

// ---------------------------------------------------------------------------
// k_p1(t): finalize(t-1) from parity-(t-1) partials (cert only when the row's
// logits were fresh at t-1; else accumulate drift), then
// Hn = select(active, LeakyReLU(Hs@W_H + drive), Hs) + dH partials.
// Grid 512 = 8 row-tiles(64) x 64 col-tiles(32).
// ---------------------------------------------------------------------------
__global__ __launch_bounds__(1024, 8) void k_p1(
    const unsigned short* __restrict__ WHThi, const unsigned short* __restrict__ WHTlo,
    const float* __restrict__ drive,
    unsigned short* __restrict__ HAhi, unsigned short* __restrict__ HAlo,
    unsigned short* __restrict__ HBhi, unsigned short* __restrict__ HBlo,
    const float* __restrict__ logits, float* __restrict__ out,
    int* __restrict__ active, int* __restrict__ cnt, const float* __restrict__ scal,
    float* __restrict__ dhp, const float* __restrict__ m1p, const float* __restrict__ m2p,
    float* __restrict__ margS, float* __restrict__ drift, const int* __restrict__ fresh,
    int t)
{
    __shared__ char lds[49152];
    __shared__ int sact[64], snew[64];
    __shared__ int s_cnt;
    const int pp = (t - 1) & 1, pc = t & 1;
    {   // frozen early-exit gate (written by p1(t-1) only)
        const int* cp = cnt + pp * 8;
        int sum = 0;
#pragma unroll
        for (int i = 0; i < 8; ++i) sum += cp[i];
        if (sum == 0) return;
    }
    const int bid = blockIdx.x, tid = threadIdx.x;
    const int rt = bid >> 6, row0m = rt << 6, col0 = (bid & 63) * 32;
    const int* actP = active + pp * BN;
    int* actC = active + pc * BN;
    const unsigned short* Hshi = (t & 1) ? HAhi : HBhi;
    const unsigned short* Hslo = (t & 1) ? HAlo : HBlo;
    unsigned short* Hnhi = (t & 1) ? HBhi : HAhi;
    unsigned short* Hnlo = (t & 1) ? HBlo : HAlo;
    const float* dhpP = dhp + (size_t)pp * BN * 64;
    float* dhpC = dhp + (size_t)pc * BN * 64;
    const float* margSP = margS + pp * BN;
    float* margSC = margS + pc * BN;
    const float* driftP = drift + pp * BN;
    float* driftC = drift + pc * BN;
    const int* freshP = fresh + pp * BN;

    // ---- finalize(t-1): certification from frozen partials ----
    if (t > 1) {
        const float gamma2 = 2.f * scal[3];
        const int rl = tid >> 4, j = tid & 15;
        const int r = row0m + rl;
        const int act = actP[r];
        const int fr = freshP[r];
        float dh = fmaxf(fmaxf(dhpP[(size_t)r * 64 + j],      dhpP[(size_t)r * 64 + 16 + j]),
                         fmaxf(dhpP[(size_t)r * 64 + 32 + j], dhpP[(size_t)r * 64 + 48 + j]));
        float M1 = m1p[(size_t)r * 32 + j], M2 = m2p[(size_t)r * 32 + j];
        {
            float o1 = m1p[(size_t)r * 32 + 16 + j], o2 = m2p[(size_t)r * 32 + 16 + j];
            if (o1 > M1) { M2 = fmaxf(M1, o2); M1 = o1; }
            else M2 = fmaxf(M2, o1);
        }
#pragma unroll
        for (int off = 1; off < 16; off <<= 1) {
            dh = fmaxf(dh, __shfl_xor(dh, off));
            float o1 = __shfl_xor(M1, off), o2 = __shfl_xor(M2, off);
            if (o1 > M1) { M2 = fmaxf(M1, o2); M1 = o1; }
            else M2 = fmaxf(M2, o1);
        }
        if (j == 0) {
            const float marg = M1 - M2;
            int nw = fr && act && (marg > gamma2 * dh);
            snew[rl] = nw;
            sact[rl] = act && !nw;
            margSC[r] = fr ? marg : margSP[r];              // pure fn of frozen state
            driftC[r] = fr ? 0.f : (driftP[r] + dh);        // identical across siblings
        }
    } else if (tid < 64) {
        sact[tid] = 1; snew[tid] = 0;
    }
    __syncthreads();
    if (tid < 64) {
        unsigned long long b = __ballot(sact[tid] != 0);
        actC[row0m + tid] = sact[tid];              // identical across 64 sibling blocks
        if (tid == 0) {
            s_cnt = __popcll(b);
            (cnt + pc * 8)[rt] = s_cnt;             // identical across siblings
        }
    }
    // newly certified rows -> out (one designated block per row-tile)
    if (t > 1 && (bid & 63) == 0) {
        for (int rl2 = 0; rl2 < 64; ++rl2) {
            if (snew[rl2]) {
                const float* lr = logits + (size_t)(row0m + rl2) * LD;
                float* orow = out + (size_t)(row0m + rl2) * LD;
                for (int jj = tid; jj < LD; jj += 1024) orow[jj] = lr[jj];
            }
        }
    }
    __syncthreads();
    if (s_cnt == 0) return;

    // ---- P1 GEMM ----
    f32x4 acc;
    int s, p;
    tile64x32<false>(nullptr, Hshi, Hslo, HDm, row0m, WHThi, WHTlo, HDm, col0, HDm,
                     lds, acc, s, p);
    const int lane = tid & 63;
    __syncthreads();
    f32x4* red = (f32x4*)lds;
    if (p == 1) red[s * 64 + lane] = acc;
    __syncthreads();
    float (*sdh)[2] = (float(*)[2])(lds + 16384);
    if (p == 0) {
        f32x4 o = red[s * 64 + lane];
        acc += o;
        const int frow = s >> 1, fcol = s & 1;
        const int gc = col0 + fcol * 16 + (lane & 15);
        const int gr0 = row0m + frow * 16 + ((lane >> 4) << 2);
        float dh4[4];
#pragma unroll
        for (int r = 0; r < 4; ++r) {
            const int gr = gr0 + r;
            const size_t idx = (size_t)gr * HDm + gc;
            const unsigned short oh = Hshi[idx], ol = Hslo[idx];
            const float old = bf2f(oh) + bf2f(ol);
            const int a = sact[gr - row0m];
            unsigned short nh, nl;
            if (a) {
                const float pre = acc[r] + drive[idx];
                const float av = pre >= 0.f ? pre : ALPHAc * pre;
                split2(av, nh, nl);
            } else { nh = oh; nl = ol; }
            Hnhi[idx] = nh; Hnlo[idx] = nl;
            dh4[r] = fabsf((bf2f(nh) + bf2f(nl)) - old);   // exactly 0 for frozen rows
        }
#pragma unroll
        for (int off = 1; off < 16; off <<= 1)
#pragma unroll
            for (int r = 0; r < 4; ++r)
                dh4[r] = fmaxf(dh4[r], __shfl_xor(dh4[r], off));
        if ((lane & 15) == 0) {
            const int rl0 = frow * 16 + ((lane >> 4) << 2);
#pragma unroll
            for (int r = 0; r < 4; ++r) sdh[rl0 + r][fcol] = dh4[r];
        }
    }
    __syncthreads();
    if (tid < 64) {
        float d = fmaxf(sdh[tid][0], sdh[tid][1]);
        dhpC[(size_t)(row0m + tid) * 64 + (bid & 63)] = d;
    }
}

// ---------------------------------------------------------------------------
// k_p2(t): Lipschitz gate, then logits = Hn @ W_HL + BL + top2 partials.
// Skip-safe: margin_t <= margS + 2*whl*(drift + dH_t); cert needs
// margin_t > 38*whl*dH_t. Grid 512 = 16 row-tiles(32) x 32 col-tiles(32).
// ---------------------------------------------------------------------------
__global__ __launch_bounds__(1024, 8) void k_p2(
    const unsigned short* __restrict__ WHLThi, const unsigned short* __restrict__ WHLTlo,
    const float* __restrict__ BL,
    const unsigned short* __restrict__ HAhi, const unsigned short* __restrict__ HAlo,
    const unsigned short* __restrict__ HBhi, const unsigned short* __restrict__ HBlo,
    float* __restrict__ logits, const int* __restrict__ active, const int* __restrict__ cnt,
    float* __restrict__ m1p, float* __restrict__ m2p, const float* __restrict__ scal,
    const float* __restrict__ dhp, const float* __restrict__ margS,
    const float* __restrict__ drift, int* __restrict__ fresh, int t)
{
    __shared__ char lds[46080];
    __shared__ int sposs[32];
    __shared__ int s_go;
    const int pc = t & 1;
    {
        const int* cp = cnt + pc * 8;
        int sum = 0;
#pragma unroll
        for (int i = 0; i < 8; ++i) sum += cp[i];
        if (sum == 0) return;
    }
    const int bid = blockIdx.x, tid = threadIdx.x;
    const unsigned short* Hnhi = (t & 1) ? HBhi : HAhi;
    const unsigned short* Hnlo = (t & 1) ? HBlo : HAlo;
    const int* actC = active + pc * BN;
    const float* dhpC = dhp + (size_t)pc * BN * 64;
    const float* margSc = margS + pc * BN;
    const float* driftc = drift + pc * BN;
    int* freshC = fresh + pc * BN;
    const int row0 = (bid >> 5) * 32, col0 = (bid & 31) * 32;

    // ---- Lipschitz impossibility gate (reads only frozen parity-pc state) ----
    {
        const int rr = tid >> 5, j = tid & 31;      // 32 rows x 32 threads
        const int r = row0 + rr;
        float d = fmaxf(dhpC[(size_t)r * 64 + j], dhpC[(size_t)r * 64 + 32 + j]);
#pragma unroll
        for (int off = 1; off < 32; off <<= 1) d = fmaxf(d, __shfl_xor(d, off));
        if (j == 0) {
            const int act = actC[r];
            int poss;
            if (t == TMAXc) poss = act;             // force last step (tail logits)
            else {
                const float whl = scal[3] * (1.f / 19.f);
                poss = act && (margSc[r] + 2.f * whl * (driftc[r] + d) >
                               0.99f * 38.f * whl * d);
            }
            sposs[rr] = poss;
        }
    }
    __syncthreads();
    if (tid < 64) {
        int v = (tid < 32) ? sposs[tid] : 0;
        unsigned long long b = __ballot(v != 0);
        if (tid == 0) s_go = (b != 0ull);
    }
    __syncthreads();
    if (tid < 32) freshC[row0 + tid] = s_go;        // identical across 32 siblings
    if (!s_go) return;

    // ---- P2 GEMM ----
    f32x4 acc;
    int s, p;
    tile32x32(Hnhi, Hnlo, row0, WHLThi, WHLTlo, col0, lds, acc, s, p);
    const int lane = tid & 63;
    __syncthreads();
    f32x4* red = (f32x4*)lds;                       // 3 x 4 x 64 x 16B = 12 KB
    if (p > 0) red[(p - 1) * 256 + s * 64 + lane] = acc;
    __syncthreads();
    float (*st1)[2] = (float(*)[2])(lds + 12288);
    float (*st2)[2] = (float(*)[2])(lds + 12544);
    if (p == 0) {
#pragma unroll
        for (int q = 0; q < 3; ++q) {
            f32x4 o = red[q * 256 + s * 64 + lane];
            acc += o;
        }
        const int frow = s >> 1, fcol = s & 1;
        const int gc = col0 + fcol * 16 + (lane & 15);
        const int gr0 = row0 + frow * 16 + ((lane >> 4) << 2);
        const bool okc = gc < LD;
        const float blv = okc ? BL[gc] : 0.f;
        float m1a[4], m2a[4];
#pragma unroll
        for (int r = 0; r < 4; ++r) {
            const float v = acc[r] + blv;
            if (okc) logits[(size_t)(gr0 + r) * LD + gc] = v;
            m1a[r] = okc ? v : -3.4e38f;
            m2a[r] = -3.4e38f;
        }
#pragma unroll
        for (int off = 1; off < 16; off <<= 1) {
#pragma unroll
            for (int r = 0; r < 4; ++r) {
                float o1 = __shfl_xor(m1a[r], off);
                float o2 = __shfl_xor(m2a[r], off);
                if (o1 > m1a[r]) { m2a[r] = fmaxf(m1a[r], o2); m1a[r] = o1; }
                else m2a[r] = fmaxf(m2a[r], o1);
            }
        }
        if ((lane & 15) == 0) {
            const int rl0 = frow * 16 + ((lane >> 4) << 2);
#pragma unroll
            for (int r = 0; r < 4; ++r) {
                st1[rl0 + r][fcol] = m1a[r];
                st2[rl0 + r][fcol] = m2a[r];
            }
        }
    }
    __syncthreads();
    if (tid < 32) {
        float M1 = st1[tid][0], M2 = st2[tid][0];
        {
            float o1 = st1[tid][1], o2 = st2[tid][1];
            if (o1 > M1) { M2 = fmaxf(M1, o2); M1 = o1; }
            else M2 = fmaxf(M2, o1);
        }
        m1p[(size_t)(row0 + tid) * 32 + (bid & 31)] = M1;
        m2p[(size_t)(row0 + tid) * 32 + (bid & 31)] = M2;
    }
}

// rows never finalized-certified take the last-step logits
__global__ __launch_bounds__(1024) void k_tail(
    const float* __restrict__ logits, const int* __restrict__ active,
    float* __restrict__ out)
{
    const int row0 = blockIdx.x * 64;
    for (int rl = 0; rl < 64; ++rl) {
        const int r = row0 + rl;
        if (active[r] && active[BN + r]) {
            const float* lr = logits + (size_t)r * LD;
            float* orow = out + (size_t)r * LD;
            for (int jj = threadIdx.x; jj < LD; jj += 1024) orow[jj] = lr[jj];
        }
    }
}

// ---------------------------------------------------------------------------
extern "C" void kernel_launch(void* const* d_in, const int* in_sizes, int n_in,
                              void* d_out, int out_size, void* d_ws, size_t ws_size,
                              hipStream_t stream)
{
    const float* x   = (const float*)d_in[0];
    const float* RIH = (const float*)d_in[1];
    const float* RH  = (const float*)d_in[2];
    const float* RHL = (const float*)d_in[3];
    const float* BH  = (const float*)d_in[4];
    const float* BL  = (const float*)d_in[5];
    const float* MIH = (const float*)d_in[6];
    const float* MH  = (const float*)d_in[7];
    const float* MHL = (const float*)d_in[8];
    float* out = (float*)d_out;
    char* w = (char*)d_ws;

    unsigned short* WHThi = (unsigned short*)(w);                 //  8 MB
    unsigned short* WHTlo = (unsigned short*)(w + 8388608);       //  8 MB
    unsigned short* WXhi  = (unsigned short*)(w + 16777216);      //  4 MB (W_IH^T then W_HL^T)
    unsigned short* WXlo  = (unsigned short*)(w + 20971520);      //  4 MB
    float* drive  = (float*)(w + 25165824);                       //  4 MB
    unsigned short* HAhi = (unsigned short*)(w + 29360128);       //  2 MB
    unsigned short* HAlo = (unsigned short*)(w + 31457280);       //  2 MB
    unsigned short* HBhi = (unsigned short*)(w + 33554432);       //  2 MB
    unsigned short* HBlo = (unsigned short*)(w + 35651584);       //  2 MB
    float* logits = (float*)(w + 37748736);                       //  2 MB (ends 39796736)
    float* scal   = (float*)(w + 39796736);                       //  32 B
    int*   active = (int*)(w + 39796800);                         //  2 x 512 x 4
    int*   cnt    = (int*)(w + 39800896);                         //  16 x 4
    float* dhp    = (float*)(w + 39800960);                       //  2 x 512 x 64 x 4 = 256 KB
    float* m1p    = (float*)(w + 40063104);                       //  512 x 32 x 4 = 64 KB
    float* m2p    = (float*)(w + 40128640);                       //  64 KB (ends 40194176)
    float* margS  = (float*)(w + 40194176);                       //  2 x 512 x 4
    float* drift  = (float*)(w + 40198272);                       //  2 x 512 x 4
    int*   fresh  = (int*)(w + 40202368);                         //  2 x 512 x 4 (ends 40206464)

    k_init<<<4, 256, 0, stream>>>(active, cnt, scal, margS, drift, fresh);
    k_colsum_wh<<<256, 256, 0, stream>>>(RH, MH, dhp);            // dhp reused as part_wh
    k_colsum_whl<<<128, 256, 0, stream>>>(RHL, MHL, m1p);         // m1p reused as part_whl
    k_scalars<<<1, 1024, 0, stream>>>(dhp, m1p, scal);
    k_wsplit<<<512, 256, 0, stream>>>(RIH, MIH, WXhi, WXlo, ID, HDm, HDm, scal, -1);
    k_drive_mfma<<<512, 1024, 0, stream>>>(x, WXhi, WXlo, BH, drive);
    k_wsplit<<<1024, 256, 0, stream>>>(RH, MH, WHThi, WHTlo, HDm, HDm, HDm, scal, 2);
    k_wsplit<<<512, 256, 0, stream>>>(RHL, MHL, WXhi, WXlo, HDm, LD, 1024, scal, -1);
    (void)hipMemsetAsync(HAhi, 0, 4194304, stream);   // zeros HAhi + HAlo (contiguous)

    for (int t = 1; t <= TMAXc; ++t) {
        k_p1<<<512, 1024, 0, stream>>>(WHThi, WHTlo, drive, HAhi, HAlo, HBhi, HBlo,
                                       logits, out, active, cnt, scal, dhp, m1p, m2p,
                                       margS, drift, fresh, t);
        k_p2<<<512, 1024, 0, stream>>>(WXhi, WXlo, BL, HAhi, HAlo, HBhi, HBlo,
                                       logits, active, cnt, m1p, m2p, scal,
                                       dhp, margS, drift, fresh, t);
    }
    k_tail<<<8, 1024, 0, stream>>>(logits, active, out);
}

// Round 13
// 1357.466 us; speedup vs baseline: 1.4498x; 1.4498x over previous
//
#include <hip/hip_runtime.h>

typedef __attribute__((ext_vector_type(8))) short short8;
typedef __attribute__((ext_vector_type(4))) float f32x4;

static constexpr int BN    = 512;
static constexpr int ID    = 1024;
static constexpr int HDm   = 2048;
static constexpr int LD    = 1000;
static constexpr int TMAXc = 32;
static constexpr float ALPHAc = 0.05f;

// ---------------- bf16 split helpers (x ~= hi + lo, each bf16) ----------------
__device__ __forceinline__ unsigned short f2bf(float x) {
    unsigned u = __float_as_uint(x);
    u += 0x7fffu + ((u >> 16) & 1u);           // RNE
    return (unsigned short)(u >> 16);
}
__device__ __forceinline__ float bf2f(unsigned short h) {
    return __uint_as_float(((unsigned)h) << 16);
}
__device__ __forceinline__ void split2(float x, unsigned short& hi, unsigned short& lo) {
    hi = f2bf(x);
    lo = f2bf(x - bf2f(hi));
}

// ---------------------------------------------------------------------------
// 64x32 tile, K-chunk 128, 1024 threads: 8 fragments (4 frow x 2 fcol) x
// 2-way K-split. 2-deep register prefetch (round-11 proven), split-bf16 MFMA.
// LDS: Ah 16K | Al 16K | Bh 8K | Bl 8K = 48 KB. Swizzle: byte ^= (row&15)<<4.
// ---------------------------------------------------------------------------
template<bool SPLITA>
__device__ __forceinline__ void tile64x32(
    const float* __restrict__ Af,
    const unsigned short* __restrict__ Ahi, const unsigned short* __restrict__ Alo,
    int lda, int row0,
    const unsigned short* __restrict__ BThi, const unsigned short* __restrict__ BTlo,
    int ldk, int col0, int K, char* lds, f32x4& acc, int& s_out, int& p_out)
{
    char* Ah = lds;
    char* Al = lds + 16384;
    char* Bh = lds + 32768;
    char* Bl = lds + 40960;
    const int t = threadIdx.x, lane = t & 63, w = t >> 6;
    const int s = w & 7, p = w >> 3;
    s_out = s; p_out = p;
    f32x4 z = {0.f, 0.f, 0.f, 0.f};
    acc = z;

    const int ar = t >> 4, ac = (t & 15) << 3;     // A: 64 rows x 128, 8 elems/stream
    const int br = t >> 5, bc = (t & 31) << 2;     // B: 32 rows x 128, 4 elems/stream
    const int asb = (ar * 256 + ac * 2) ^ ((ar & 15) << 4);
    const int bsb = (br * 256 + bc * 2) ^ ((br & 15) << 4);
    const float* Ap = SPLITA ? (Af + (size_t)(row0 + ar) * lda + ac) : nullptr;
    const unsigned short* Ahp = SPLITA ? nullptr : (Ahi + (size_t)(row0 + ar) * lda + ac);
    const unsigned short* Alp = SPLITA ? nullptr : (Alo + (size_t)(row0 + ar) * lda + ac);
    const unsigned short* Bhp = BThi + (size_t)(col0 + br) * ldk + bc;
    const unsigned short* Blp = BTlo + (size_t)(col0 + br) * ldk + bc;

    const int frow = s >> 1, fcol = s & 1;
    const int arow = frow * 16 + (lane & 15);
    const int colr = fcol * 16 + (lane & 15);
    const int ab0 = arow * 256, bb0 = colr * 256;
    const int axor = (arow & 15) << 4, bxor = (colr & 15) << 4;
    const int kwin = p * 128 + ((lane >> 4) << 4);

    float4 af0a, af0b, af1a, af1b;
    uint4 ah0, al0, ah1, al1;
    if constexpr (SPLITA) {
        af0a = *(const float4*)(Ap);       af0b = *(const float4*)(Ap + 4);
        af1a = *(const float4*)(Ap + 128); af1b = *(const float4*)(Ap + 132);
    } else {
        ah0 = *(const uint4*)(Ahp);       al0 = *(const uint4*)(Alp);
        ah1 = *(const uint4*)(Ahp + 128); al1 = *(const uint4*)(Alp + 128);
    }
    uint2 bh0 = *(const uint2*)(Bhp),       bl0 = *(const uint2*)(Blp);
    uint2 bh1 = *(const uint2*)(Bhp + 128), bl1 = *(const uint2*)(Blp + 128);

    for (int k0 = 0; k0 < K; k0 += 128) {
        uint4 awh, awl;
        if constexpr (SPLITA) {
            unsigned short h[8], l[8];
            const float vv[8] = {af0a.x, af0a.y, af0a.z, af0a.w,
                                 af0b.x, af0b.y, af0b.z, af0b.w};
#pragma unroll
            for (int i = 0; i < 8; ++i) split2(vv[i], h[i], l[i]);
            awh = make_uint4((unsigned)h[0] | ((unsigned)h[1] << 16),
                             (unsigned)h[2] | ((unsigned)h[3] << 16),
                             (unsigned)h[4] | ((unsigned)h[5] << 16),
                             (unsigned)h[6] | ((unsigned)h[7] << 16));
            awl = make_uint4((unsigned)l[0] | ((unsigned)l[1] << 16),
                             (unsigned)l[2] | ((unsigned)l[3] << 16),
                             (unsigned)l[4] | ((unsigned)l[5] << 16),
                             (unsigned)l[6] | ((unsigned)l[7] << 16));
        } else { awh = ah0; awl = al0; }
        const uint2 bwh = bh0, bwl = bl0;
        __syncthreads();                            // prior LDS readers done
        *(uint4*)(Ah + asb) = awh;
        *(uint4*)(Al + asb) = awl;
        *(uint2*)(Bh + bsb) = bwh;
        *(uint2*)(Bl + bsb) = bwl;
        if constexpr (SPLITA) { af0a = af1a; af0b = af1b; } else { ah0 = ah1; al0 = al1; }
        bh0 = bh1; bl0 = bl1;
        if (k0 + 256 < K) {
            if constexpr (SPLITA) {
                af1a = *(const float4*)(Ap + k0 + 256);
                af1b = *(const float4*)(Ap + k0 + 260);
            } else {
                ah1 = *(const uint4*)(Ahp + k0 + 256);
                al1 = *(const uint4*)(Alp + k0 + 256);
            }
            bh1 = *(const uint2*)(Bhp + k0 + 256);
            bl1 = *(const uint2*)(Blp + k0 + 256);
        }
        __syncthreads();
#pragma unroll
        for (int ks = 0; ks < 2; ++ks) {
            const int kb = kwin + ks * 64;
            short8 bh = *(const short8*)(Bh + ((bb0 + kb) ^ bxor));
            short8 bl = *(const short8*)(Bl + ((bb0 + kb) ^ bxor));
            short8 ah = *(const short8*)(Ah + ((ab0 + kb) ^ axor));
            short8 al = *(const short8*)(Al + ((ab0 + kb) ^ axor));
            acc = __builtin_amdgcn_mfma_f32_16x16x32_bf16(ah, bh, acc, 0, 0, 0);
            acc = __builtin_amdgcn_mfma_f32_16x16x32_bf16(al, bh, acc, 0, 0, 0);
            acc = __builtin_amdgcn_mfma_f32_16x16x32_bf16(ah, bl, acc, 0, 0, 0);
        }
    }
}

// ---------------------------------------------------------------------------
// 32x32 tile, K-chunk 128, 1024 threads: 4 fragments x 4-way K-split (p=w>>2).
// LDS: Ah 8K | Al 8K | Bh 8K | Bl 8K = 32 KB (+12 KB reduce region after).
// ---------------------------------------------------------------------------
__device__ __forceinline__ void tile32x32(
    const unsigned short* __restrict__ Ahi, const unsigned short* __restrict__ Alo, int row0,
    const unsigned short* __restrict__ BThi, const unsigned short* __restrict__ BTlo,
    int col0, char* lds, f32x4& acc, int& s_out, int& p_out)
{
    char* Ah = lds;
    char* Al = lds + 8192;
    char* Bh = lds + 16384;
    char* Bl = lds + 24576;
    const int t = threadIdx.x, lane = t & 63, w = t >> 6;
    const int s = w & 3, p = w >> 2;
    s_out = s; p_out = p;
    f32x4 z = {0.f, 0.f, 0.f, 0.f};
    acc = z;

    const int ar = t >> 5, ac = (t & 31) << 2;     // 32 rows x 128, 4 elems/stream
    const int asb = (ar * 256 + ac * 2) ^ ((ar & 15) << 4);
    const unsigned short* Ahp = Ahi + (size_t)(row0 + ar) * HDm + ac;
    const unsigned short* Alp = Alo + (size_t)(row0 + ar) * HDm + ac;
    const unsigned short* Bhp = BThi + (size_t)(col0 + ar) * HDm + ac;
    const unsigned short* Blp = BTlo + (size_t)(col0 + ar) * HDm + ac;

    const int frow = s >> 1, fcol = s & 1;
    const int arow = frow * 16 + (lane & 15);
    const int colr = fcol * 16 + (lane & 15);
    const int ab0 = arow * 256, bb0 = colr * 256;
    const int axor = (arow & 15) << 4, bxor = (colr & 15) << 4;
    const int kwin = p * 64 + ((lane >> 4) << 4);

    uint2 ah0 = *(const uint2*)(Ahp),       al0 = *(const uint2*)(Alp);
    uint2 bh0 = *(const uint2*)(Bhp),       bl0 = *(const uint2*)(Blp);
    uint2 ah1 = *(const uint2*)(Ahp + 128), al1 = *(const uint2*)(Alp + 128);
    uint2 bh1 = *(const uint2*)(Bhp + 128), bl1 = *(const uint2*)(Blp + 128);

    for (int k0 = 0; k0 < HDm; k0 += 128) {
        const uint2 awh = ah0, awl = al0, bwh = bh0, bwl = bl0;
        __syncthreads();
        *(uint2*)(Ah + asb) = awh;
        *(uint2*)(Al + asb) = awl;
        *(uint2*)(Bh + asb) = bwh;
        *(uint2*)(Bl + asb) = bwl;
        ah0 = ah1; al0 = al1; bh0 = bh1; bl0 = bl1;
        if (k0 + 256 < HDm) {
            ah1 = *(const uint2*)(Ahp + k0 + 256);
            al1 = *(const uint2*)(Alp + k0 + 256);
            bh1 = *(const uint2*)(Bhp + k0 + 256);
            bl1 = *(const uint2*)(Blp + k0 + 256);
        }
        __syncthreads();
        const int kb = kwin;
        short8 bh = *(const short8*)(Bh + ((bb0 + kb) ^ bxor));
        short8 bl = *(const short8*)(Bl + ((bb0 + kb) ^ bxor));
        short8 ah = *(const short8*)(Ah + ((ab0 + kb) ^ axor));
        short8 al = *(const short8*)(Al + ((ab0 + kb) ^ axor));
        acc = __builtin_amdgcn_mfma_f32_16x16x32_bf16(ah, bh, acc, 0, 0, 0);
        acc = __builtin_amdgcn_mfma_f32_16x16x32_bf16(al, bh, acc, 0, 0, 0);
        acc = __builtin_amdgcn_mfma_f32_16x16x32_bf16(ah, bl, acc, 0, 0, 0);
    }
}

// ---------------------------------------------------------------------------
// Prep kernels
// ---------------------------------------------------------------------------
__global__ void k_init(int* active, int* cnt, float* scal,
                       float* margS, float* drift, int* fresh)
{
    int i = blockIdx.x * blockDim.x + threadIdx.x;
    if (i < 2 * BN) {
        active[i] = 1;
        margS[i] = 3.4e38f;
        drift[i] = 0.f;
        fresh[i] = 1;
    }
    if (i < 16) cnt[i] = 64;
    if (i < 8) scal[i] = 0.f;
}

__global__ __launch_bounds__(256) void k_colsum_wh(const float* __restrict__ RH,
                                                   const float* __restrict__ MH,
                                                   float* __restrict__ part)
{
    const int colTile = blockIdx.x >> 3, rs = blockIdx.x & 7;
    const int col = colTile * 64 + (threadIdx.x & 63);
    const int rq = threadIdx.x >> 6;
    const int r0 = rs * 256;
    float s = 0.f;
    for (int i = r0 + rq; i < r0 + 256; i += 4)
        s += fabsf(RH[(size_t)i * HDm + col] * MH[(size_t)i * HDm + col]);
    __shared__ float red[4][64];
    red[rq][threadIdx.x & 63] = s;
    __syncthreads();
    if (threadIdx.x < 64)
        part[(size_t)rs * HDm + col] = red[0][threadIdx.x] + red[1][threadIdx.x] +
                                       red[2][threadIdx.x] + red[3][threadIdx.x];
}

__global__ __launch_bounds__(256) void k_colsum_whl(const float* __restrict__ RHL,
                                                    const float* __restrict__ MHL,
                                                    float* __restrict__ part)
{
    const int colTile = blockIdx.x >> 3, rs = blockIdx.x & 7;
    const int col = colTile * 64 + (threadIdx.x & 63);
    const int rq = threadIdx.x >> 6;
    const int r0 = rs * 256;
    float s = 0.f;
    if (col < LD) {
        for (int i = r0 + rq; i < r0 + 256; i += 4)
            s += fabsf(RHL[(size_t)i * LD + col] * MHL[(size_t)i * LD + col]);
    }
    __shared__ float red[4][64];
    red[rq][threadIdx.x & 63] = s;
    __syncthreads();
    if (threadIdx.x < 64)
        part[(size_t)rs * 1024 + col] = red[0][threadIdx.x] + red[1][threadIdx.x] +
                                        red[2][threadIdx.x] + red[3][threadIdx.x];
}

__global__ __launch_bounds__(1024) void k_scalars(const float* __restrict__ part_wh,
                                                  const float* __restrict__ part_whl,
                                                  float* scal)
{
    float m1 = 0.f, m2 = 0.f;
    for (int c = threadIdx.x; c < HDm; c += 1024) {
        float s = 0.f;
#pragma unroll
        for (int k = 0; k < 8; ++k) s += part_wh[(size_t)k * HDm + c];
        m1 = fmaxf(m1, s);
    }
    {
        const int c = threadIdx.x;
        if (c < 1024) {
            float s = 0.f;
#pragma unroll
            for (int k = 0; k < 8; ++k) s += part_whl[(size_t)k * 1024 + c];
            m2 = fmaxf(m2, s);
        }
    }
#pragma unroll
    for (int off = 1; off < 64; off <<= 1) {
        m1 = fmaxf(m1, __shfl_xor(m1, off));
        m2 = fmaxf(m2, __shfl_xor(m2, off));
    }
    __shared__ float r1[16], r2[16];
    if ((threadIdx.x & 63) == 0) { r1[threadIdx.x >> 6] = m1; r2[threadIdx.x >> 6] = m2; }
    __syncthreads();
    if (threadIdx.x == 0) {
        float a = 0.f, b = 0.f;
#pragma unroll
        for (int i = 0; i < 16; ++i) { a = fmaxf(a, r1[i]); b = fmaxf(b, r2[i]); }
        scal[2] = 0.95f / fmaxf(a, 1e-8f);
        scal[3] = b * 19.f;
    }
}

// Transposed split:  O{hi,lo}[c][r] = split(R[r][c] * M[r][c] * s)
__global__ __launch_bounds__(256) void k_wsplit(
    const float* __restrict__ R, const float* __restrict__ M,
    unsigned short* __restrict__ Ohi, unsigned short* __restrict__ Olo,
    int NR, int NC, int NCp, const float* __restrict__ scal, int scidx)
{
    __shared__ float T[64][65];
    const int nct = NCp >> 6;
    const int c0 = (blockIdx.x % nct) << 6;
    const int r0 = (blockIdx.x / nct) << 6;
    const float s = (scidx >= 0) ? scal[scidx] : 1.f;
    const int t = threadIdx.x;
    const int ir = t >> 2, ics = (t & 3) << 4;
#pragma unroll
    for (int i = 0; i < 16; ++i) {
        const int c = c0 + ics + i;
        float v = 0.f;
        if (c < NC) {
            const size_t idx = (size_t)(r0 + ir) * NC + c;
            v = R[idx] * M[idx] * s;
        }
        T[ir][ics + i] = v;
    }
    __syncthreads();
    const int oc = t >> 2, ors = (t & 3) << 4;
    unsigned short hb[16], lb[16];
#pragma unroll
    for (int i = 0; i < 16; ++i) split2(T[ors + i][oc], hb[i], lb[i]);
    const size_t base = (size_t)(c0 + oc) * NR + r0 + ors;
    uint4 v;
    v.x = hb[0] | ((unsigned)hb[1] << 16);  v.y = hb[2] | ((unsigned)hb[3] << 16);
    v.z = hb[4] | ((unsigned)hb[5] << 16);  v.w = hb[6] | ((unsigned)hb[7] << 16);
    *(uint4*)(Ohi + base) = v;
    v.x = hb[8] | ((unsigned)hb[9] << 16);  v.y = hb[10] | ((unsigned)hb[11] << 16);
    v.z = hb[12] | ((unsigned)hb[13] << 16); v.w = hb[14] | ((unsigned)hb[15] << 16);
    *(uint4*)(Ohi + base + 8) = v;
    v.x = lb[0] | ((unsigned)lb[1] << 16);  v.y = lb[2] | ((unsigned)lb[3] << 16);
    v.z = lb[4] | ((unsigned)lb[5] << 16);  v.w = lb[6] | ((unsigned)lb[7] << 16);
    *(uint4*)(Olo + base) = v;
    v.x = lb[8] | ((unsigned)lb[9] << 16);  v.y = lb[10] | ((unsigned)lb[11] << 16);
    v.z = lb[12] | ((unsigned)lb[13] << 16); v.w = lb[14] | ((unsigned)lb[15] << 16);
    *(uint4*)(Olo + base + 8) = v;
}

// drive = x @ W_IH + BH   (512 blocks = 8 x 64 tiles of 64x32, K=1024)
__global__ __launch_bounds__(1024, 8) void k_drive_mfma(
    const float* __restrict__ x,
    const unsigned short* __restrict__ WIHThi, const unsigned short* __restrict__ WIHTlo,
    const float* __restrict__ BH, float* __restrict__ drive)
{
    __shared__ char lds[49152];
    f32x4 acc;
    int s, p;
    const int row0 = (blockIdx.x >> 6) * 64, col0 = (blockIdx.x & 63) * 32;
    tile64x32<true>(x, nullptr, nullptr, ID, row0, WIHThi, WIHTlo, ID, col0, ID,
                    lds, acc, s, p);
    const int lane = threadIdx.x & 63;
    __syncthreads();
    f32x4* red = (f32x4*)lds;
    if (p == 1) red[s * 64 + lane] = acc;
    __syncthreads();
    if (p == 0) {
        f32x4 o = red[s * 64 + lane];
        acc += o;
        const int frow = s >> 1, fcol = s & 1;
        const int gc = col0 + fcol * 16 + (lane & 15);
        const int gr0 = row0 + frow * 16 + ((lane >> 4) << 2);
        const float bh = BH[gc];
#pragma unroll
        for (int r = 0; r < 4; ++r)
            drive[(size_t)(gr0 + r) * HDm + gc] = acc[r] + bh;
    }
}

// ---------------------------------------------------------------------------
// k_p1(t): finalize(t-1) from parity-(t-1) partials (cert only when the row's
// logits were fresh at t-1; else accumulate drift), then
// Hn = select(active, LeakyReLU(Hs@W_H + drive), Hs) + dH partials.
// Grid 512 = 8 row-tiles(64) x 64 col-tiles(32).
// ---------------------------------------------------------------------------
__global__ __launch_bounds__(1024, 8) void k_p1(
    const unsigned short* __restrict__ WHThi, const unsigned short* __restrict__ WHTlo,
    const float* __restrict__ drive,
    unsigned short* __restrict__ HAhi, unsigned short* __restrict__ HAlo,
    unsigned short* __restrict__ HBhi, unsigned short* __restrict__ HBlo,
    const float* __restrict__ logits, float* __restrict__ out,
    int* __restrict__ active, int* __restrict__ cnt, const float* __restrict__ scal,
    float* __restrict__ dhp, const float* __restrict__ m1p, const float* __restrict__ m2p,
    float* __restrict__ margS, float* __restrict__ drift, const int* __restrict__ fresh,
    int t)
{
    __shared__ char lds[49152];
    __shared__ int sact[64], snew[64];
    __shared__ int s_cnt;
    const int pp = (t - 1) & 1, pc = t & 1;
    {   // frozen early-exit gate (written by p1(t-1) only)
        const int* cp = cnt + pp * 8;
        int sum = 0;
#pragma unroll
        for (int i = 0; i < 8; ++i) sum += cp[i];
        if (sum == 0) return;
    }
    const int bid = blockIdx.x, tid = threadIdx.x;
    const int rt = bid >> 6, row0m = rt << 6, col0 = (bid & 63) * 32;
    const int* actP = active + pp * BN;
    int* actC = active + pc * BN;
    const unsigned short* Hshi = (t & 1) ? HAhi : HBhi;
    const unsigned short* Hslo = (t & 1) ? HAlo : HBlo;
    unsigned short* Hnhi = (t & 1) ? HBhi : HAhi;
    unsigned short* Hnlo = (t & 1) ? HBlo : HAlo;
    const float* dhpP = dhp + (size_t)pp * BN * 64;
    float* dhpC = dhp + (size_t)pc * BN * 64;
    const float* margSP = margS + pp * BN;
    float* margSC = margS + pc * BN;
    const float* driftP = drift + pp * BN;
    float* driftC = drift + pc * BN;
    const int* freshP = fresh + pp * BN;

    // ---- finalize(t-1): certification from frozen partials ----
    if (t > 1) {
        const float gamma2 = 2.f * scal[3];
        const int rl = tid >> 4, j = tid & 15;
        const int r = row0m + rl;
        const int act = actP[r];
        const int fr = freshP[r];
        float dh = fmaxf(fmaxf(dhpP[(size_t)r * 64 + j],      dhpP[(size_t)r * 64 + 16 + j]),
                         fmaxf(dhpP[(size_t)r * 64 + 32 + j], dhpP[(size_t)r * 64 + 48 + j]));
        float M1 = m1p[(size_t)r * 32 + j], M2 = m2p[(size_t)r * 32 + j];
        {
            float o1 = m1p[(size_t)r * 32 + 16 + j], o2 = m2p[(size_t)r * 32 + 16 + j];
            if (o1 > M1) { M2 = fmaxf(M1, o2); M1 = o1; }
            else M2 = fmaxf(M2, o1);
        }
#pragma unroll
        for (int off = 1; off < 16; off <<= 1) {
            dh = fmaxf(dh, __shfl_xor(dh, off));
            float o1 = __shfl_xor(M1, off), o2 = __shfl_xor(M2, off);
            if (o1 > M1) { M2 = fmaxf(M1, o2); M1 = o1; }
            else M2 = fmaxf(M2, o1);
        }
        if (j == 0) {
            const float marg = M1 - M2;
            int nw = fr && act && (marg > gamma2 * dh);
            snew[rl] = nw;
            sact[rl] = act && !nw;
            margSC[r] = fr ? marg : margSP[r];              // pure fn of frozen state
            driftC[r] = fr ? 0.f : (driftP[r] + dh);        // identical across siblings
        }
    } else if (tid < 64) {
        sact[tid] = 1; snew[tid] = 0;
    }
    __syncthreads();
    if (tid < 64) {
        unsigned long long b = __ballot(sact[tid] != 0);
        actC[row0m + tid] = sact[tid];              // identical across 64 sibling blocks
        if (tid == 0) {
            s_cnt = __popcll(b);
            (cnt + pc * 8)[rt] = s_cnt;             // identical across siblings
        }
    }
    // newly certified rows -> out (one designated block per row-tile)
    if (t > 1 && (bid & 63) == 0) {
        for (int rl2 = 0; rl2 < 64; ++rl2) {
            if (snew[rl2]) {
                const float* lr = logits + (size_t)(row0m + rl2) * LD;
                float* orow = out + (size_t)(row0m + rl2) * LD;
                for (int jj = tid; jj < LD; jj += 1024) orow[jj] = lr[jj];
            }
        }
    }
    __syncthreads();
    if (s_cnt == 0) return;

    // ---- P1 GEMM ----
    f32x4 acc;
    int s, p;
    tile64x32<false>(nullptr, Hshi, Hslo, HDm, row0m, WHThi, WHTlo, HDm, col0, HDm,
                     lds, acc, s, p);
    const int lane = tid & 63;
    __syncthreads();
    f32x4* red = (f32x4*)lds;
    if (p == 1) red[s * 64 + lane] = acc;
    __syncthreads();
    float (*sdh)[2] = (float(*)[2])(lds + 16384);
    if (p == 0) {
        f32x4 o = red[s * 64 + lane];
        acc += o;
        const int frow = s >> 1, fcol = s & 1;
        const int gc = col0 + fcol * 16 + (lane & 15);
        const int gr0 = row0m + frow * 16 + ((lane >> 4) << 2);
        float dh4[4];
#pragma unroll
        for (int r = 0; r < 4; ++r) {
            const int gr = gr0 + r;
            const size_t idx = (size_t)gr * HDm + gc;
            const unsigned short oh = Hshi[idx], ol = Hslo[idx];
            const float old = bf2f(oh) + bf2f(ol);
            const int a = sact[gr - row0m];
            unsigned short nh, nl;
            if (a) {
                const float pre = acc[r] + drive[idx];
                const float av = pre >= 0.f ? pre : ALPHAc * pre;
                split2(av, nh, nl);
            } else { nh = oh; nl = ol; }
            Hnhi[idx] = nh; Hnlo[idx] = nl;
            dh4[r] = fabsf((bf2f(nh) + bf2f(nl)) - old);   // exactly 0 for frozen rows
        }
#pragma unroll
        for (int off = 1; off < 16; off <<= 1)
#pragma unroll
            for (int r = 0; r < 4; ++r)
                dh4[r] = fmaxf(dh4[r], __shfl_xor(dh4[r], off));
        if ((lane & 15) == 0) {
            const int rl0 = frow * 16 + ((lane >> 4) << 2);
#pragma unroll
            for (int r = 0; r < 4; ++r) sdh[rl0 + r][fcol] = dh4[r];
        }
    }
    __syncthreads();
    if (tid < 64) {
        float d = fmaxf(sdh[tid][0], sdh[tid][1]);
        dhpC[(size_t)(row0m + tid) * 64 + (bid & 63)] = d;
    }
}

// ---------------------------------------------------------------------------
// k_p2(t): Lipschitz gate, then logits = Hn @ W_HL + BL + top2 partials.
// Skip-safe: margin_t <= margS + 2*whl*(drift + dH_t); cert needs
// margin_t > 38*whl*dH_t. Grid 512 = 16 row-tiles(32) x 32 col-tiles(32).
// ---------------------------------------------------------------------------
__global__ __launch_bounds__(1024, 8) void k_p2(
    const unsigned short* __restrict__ WHLThi, const unsigned short* __restrict__ WHLTlo,
    const float* __restrict__ BL,
    const unsigned short* __restrict__ HAhi, const unsigned short* __restrict__ HAlo,
    const unsigned short* __restrict__ HBhi, const unsigned short* __restrict__ HBlo,
    float* __restrict__ logits, const int* __restrict__ active, const int* __restrict__ cnt,
    float* __restrict__ m1p, float* __restrict__ m2p, const float* __restrict__ scal,
    const float* __restrict__ dhp, const float* __restrict__ margS,
    const float* __restrict__ drift, int* __restrict__ fresh, int t)
{
    __shared__ char lds[46080];
    __shared__ int sposs[32];
    __shared__ int s_go;
    const int pc = t & 1;
    {
        const int* cp = cnt + pc * 8;
        int sum = 0;
#pragma unroll
        for (int i = 0; i < 8; ++i) sum += cp[i];
        if (sum == 0) return;
    }
    const int bid = blockIdx.x, tid = threadIdx.x;
    const unsigned short* Hnhi = (t & 1) ? HBhi : HAhi;
    const unsigned short* Hnlo = (t & 1) ? HBlo : HAlo;
    const int* actC = active + pc * BN;
    const float* dhpC = dhp + (size_t)pc * BN * 64;
    const float* margSc = margS + pc * BN;
    const float* driftc = drift + pc * BN;
    int* freshC = fresh + pc * BN;
    const int row0 = (bid >> 5) * 32, col0 = (bid & 31) * 32;

    // ---- Lipschitz impossibility gate (reads only frozen parity-pc state) ----
    {
        const int rr = tid >> 5, j = tid & 31;      // 32 rows x 32 threads
        const int r = row0 + rr;
        float d = fmaxf(dhpC[(size_t)r * 64 + j], dhpC[(size_t)r * 64 + 32 + j]);
#pragma unroll
        for (int off = 1; off < 32; off <<= 1) d = fmaxf(d, __shfl_xor(d, off));
        if (j == 0) {
            const int act = actC[r];
            int poss;
            if (t == TMAXc) poss = act;             // force last step (tail logits)
            else {
                const float whl = scal[3] * (1.f / 19.f);
                poss = act && (margSc[r] + 2.f * whl * (driftc[r] + d) >
                               0.99f * 38.f * whl * d);
            }
            sposs[rr] = poss;
        }
    }
    __syncthreads();
    if (tid < 64) {
        int v = (tid < 32) ? sposs[tid] : 0;
        unsigned long long b = __ballot(v != 0);
        if (tid == 0) s_go = (b != 0ull);
    }
    __syncthreads();
    if (tid < 32) freshC[row0 + tid] = s_go;        // identical across 32 siblings
    if (!s_go) return;

    // ---- P2 GEMM ----
    f32x4 acc;
    int s, p;
    tile32x32(Hnhi, Hnlo, row0, WHLThi, WHLTlo, col0, lds, acc, s, p);
    const int lane = tid & 63;
    __syncthreads();
    f32x4* red = (f32x4*)lds;                       // 3 x 4 x 64 x 16B = 12 KB
    if (p > 0) red[(p - 1) * 256 + s * 64 + lane] = acc;
    __syncthreads();
    float (*st1)[2] = (float(*)[2])(lds + 12288);
    float (*st2)[2] = (float(*)[2])(lds + 12544);
    if (p == 0) {
#pragma unroll
        for (int q = 0; q < 3; ++q) {
            f32x4 o = red[q * 256 + s * 64 + lane];
            acc += o;
        }
        const int frow = s >> 1, fcol = s & 1;
        const int gc = col0 + fcol * 16 + (lane & 15);
        const int gr0 = row0 + frow * 16 + ((lane >> 4) << 2);
        const bool okc = gc < LD;
        const float blv = okc ? BL[gc] : 0.f;
        float m1a[4], m2a[4];
#pragma unroll
        for (int r = 0; r < 4; ++r) {
            const float v = acc[r] + blv;
            if (okc) logits[(size_t)(gr0 + r) * LD + gc] = v;
            m1a[r] = okc ? v : -3.4e38f;
            m2a[r] = -3.4e38f;
        }
#pragma unroll
        for (int off = 1; off < 16; off <<= 1) {
#pragma unroll
            for (int r = 0; r < 4; ++r) {
                float o1 = __shfl_xor(m1a[r], off);
                float o2 = __shfl_xor(m2a[r], off);
                if (o1 > m1a[r]) { m2a[r] = fmaxf(m1a[r], o2); m1a[r] = o1; }
                else m2a[r] = fmaxf(m2a[r], o1);
            }
        }
        if ((lane & 15) == 0) {
            const int rl0 = frow * 16 + ((lane >> 4) << 2);
#pragma unroll
            for (int r = 0; r < 4; ++r) {
                st1[rl0 + r][fcol] = m1a[r];
                st2[rl0 + r][fcol] = m2a[r];
            }
        }
    }
    __syncthreads();
    if (tid < 32) {
        float M1 = st1[tid][0], M2 = st2[tid][0];
        {
            float o1 = st1[tid][1], o2 = st2[tid][1];
            if (o1 > M1) { M2 = fmaxf(M1, o2); M1 = o1; }
            else M2 = fmaxf(M2, o1);
        }
        m1p[(size_t)(row0 + tid) * 32 + (bid & 31)] = M1;
        m2p[(size_t)(row0 + tid) * 32 + (bid & 31)] = M2;
    }
}

// rows never finalized-certified take the last-step logits
__global__ __launch_bounds__(1024) void k_tail(
    const float* __restrict__ logits, const int* __restrict__ active,
    float* __restrict__ out)
{
    const int row0 = blockIdx.x * 64;
    for (int rl = 0; rl < 64; ++rl) {
        const int r = row0 + rl;
        if (active[r] && active[BN + r]) {
            const float* lr = logits + (size_t)r * LD;
            float* orow = out + (size_t)r * LD;
            for (int jj = threadIdx.x; jj < LD; jj += 1024) orow[jj] = lr[jj];
        }
    }
}

// ---------------------------------------------------------------------------
extern "C" void kernel_launch(void* const* d_in, const int* in_sizes, int n_in,
                              void* d_out, int out_size, void* d_ws, size_t ws_size,
                              hipStream_t stream)
{
    const float* x   = (const float*)d_in[0];
    const float* RIH = (const float*)d_in[1];
    const float* RH  = (const float*)d_in[2];
    const float* RHL = (const float*)d_in[3];
    const float* BH  = (const float*)d_in[4];
    const float* BL  = (const float*)d_in[5];
    const float* MIH = (const float*)d_in[6];
    const float* MH  = (const float*)d_in[7];
    const float* MHL = (const float*)d_in[8];
    float* out = (float*)d_out;
    char* w = (char*)d_ws;

    unsigned short* WHThi = (unsigned short*)(w);                 //  8 MB
    unsigned short* WHTlo = (unsigned short*)(w + 8388608);       //  8 MB
    unsigned short* WXhi  = (unsigned short*)(w + 16777216);      //  4 MB (W_IH^T then W_HL^T)
    unsigned short* WXlo  = (unsigned short*)(w + 20971520);      //  4 MB
    float* drive  = (float*)(w + 25165824);                       //  4 MB
    unsigned short* HAhi = (unsigned short*)(w + 29360128);       //  2 MB
    unsigned short* HAlo = (unsigned short*)(w + 31457280);       //  2 MB
    unsigned short* HBhi = (unsigned short*)(w + 33554432);       //  2 MB
    unsigned short* HBlo = (unsigned short*)(w + 35651584);       //  2 MB
    float* logits = (float*)(w + 37748736);                       //  2 MB (ends 39796736)
    float* scal   = (float*)(w + 39796736);                       //  32 B
    int*   active = (int*)(w + 39796800);                         //  2 x 512 x 4
    int*   cnt    = (int*)(w + 39800896);                         //  16 x 4
    float* dhp    = (float*)(w + 39800960);                       //  2 x 512 x 64 x 4 = 256 KB
    float* m1p    = (float*)(w + 40063104);                       //  512 x 32 x 4 = 64 KB
    float* m2p    = (float*)(w + 40128640);                       //  64 KB (ends 40194176)
    float* margS  = (float*)(w + 40194176);                       //  2 x 512 x 4
    float* drift  = (float*)(w + 40198272);                       //  2 x 512 x 4
    int*   fresh  = (int*)(w + 40202368);                         //  2 x 512 x 4 (ends 40206464)

    k_init<<<4, 256, 0, stream>>>(active, cnt, scal, margS, drift, fresh);
    k_colsum_wh<<<256, 256, 0, stream>>>(RH, MH, dhp);            // dhp reused as part_wh
    k_colsum_whl<<<128, 256, 0, stream>>>(RHL, MHL, m1p);         // m1p reused as part_whl
    k_scalars<<<1, 1024, 0, stream>>>(dhp, m1p, scal);
    k_wsplit<<<512, 256, 0, stream>>>(RIH, MIH, WXhi, WXlo, ID, HDm, HDm, scal, -1);
    k_drive_mfma<<<512, 1024, 0, stream>>>(x, WXhi, WXlo, BH, drive);
    k_wsplit<<<1024, 256, 0, stream>>>(RH, MH, WHThi, WHTlo, HDm, HDm, HDm, scal, 2);
    k_wsplit<<<512, 256, 0, stream>>>(RHL, MHL, WXhi, WXlo, HDm, LD, 1024, scal, -1);
    (void)hipMemsetAsync(HAhi, 0, 4194304, stream);   // zeros HAhi + HAlo (contiguous)

    for (int t = 1; t <= TMAXc; ++t) {
        k_p1<<<512, 1024, 0, stream>>>(WHThi, WHTlo, drive, HAhi, HAlo, HBhi, HBlo,
                                       logits, out, active, cnt, scal, dhp, m1p, m2p,
                                       margS, drift, fresh, t);
        k_p2<<<512, 1024, 0, stream>>>(WXhi, WXlo, BL, HAhi, HAlo, HBhi, HBlo,
                                       logits, active, cnt, m1p, m2p, scal,
                                       dhp, margS, drift, fresh, t);
    }
    k_tail<<<8, 1024, 0, stream>>>(logits, active, out);
}

// Round 14
// 1334.149 us; speedup vs baseline: 1.4752x; 1.0175x over previous
//
#include <hip/hip_runtime.h>

typedef __attribute__((ext_vector_type(8))) short short8;
typedef __attribute__((ext_vector_type(4))) float f32x4;

static constexpr int BN    = 512;
static constexpr int ID    = 1024;
static constexpr int HDm   = 2048;
static constexpr int LD    = 1000;
static constexpr int TMAXc = 32;
static constexpr float ALPHAc = 0.05f;

// ---------------- bf16 split helpers (x ~= hi + lo, each bf16) ----------------
__device__ __forceinline__ unsigned short f2bf(float x) {
    unsigned u = __float_as_uint(x);
    u += 0x7fffu + ((u >> 16) & 1u);           // RNE
    return (unsigned short)(u >> 16);
}
__device__ __forceinline__ float bf2f(unsigned short h) {
    return __uint_as_float(((unsigned)h) << 16);
}
__device__ __forceinline__ void split2(float x, unsigned short& hi, unsigned short& lo) {
    hi = f2bf(x);
    lo = f2bf(x - bf2f(hi));
}

// async global->LDS DMA, 16B per lane; LDS dest = base + lane*16 (wave-uniform base)
__device__ __forceinline__ void gload16(const void* g, void* l) {
    __builtin_amdgcn_global_load_lds(
        (const __attribute__((address_space(1))) unsigned int*)g,
        (__attribute__((address_space(3))) unsigned int*)l, 16, 0, 0);
}

// Image layout (per 32-row x 128-k chunk, 8 KB per array):
//   img[(row*256 + k*2) ^ ((row&15)<<4)] = bf16 element (row, k)
// A 64-row tile image (16 KB) = two consecutive 32-row images (swizzle uses row&15).

// H image byte offset for global element (gr, gc); nkc=16 chunks of 128.
__device__ __forceinline__ size_t himg_off(int gr, int gc) {
    const int rt = gr >> 6, ar = gr & 63, kc = gc >> 7, ac = gc & 127;
    const int byte = (ar * 256 + ac * 2) ^ ((ar & 15) << 4);
    return ((size_t)(rt * 16 + kc) << 14) + byte;
}

// ---------------------------------------------------------------------------
// Drive tile (runs once): 64x32, fp32 A register-split, linear-layout B,
// 2-deep prefetch (round-11 proven).
// ---------------------------------------------------------------------------
__device__ __forceinline__ void tile64_drive(
    const float* __restrict__ Af, int lda, int row0,
    const unsigned short* __restrict__ BThi, const unsigned short* __restrict__ BTlo,
    int ldk, int col0, int K, char* lds, f32x4& acc, int& s_out, int& p_out)
{
    char* Ah = lds;
    char* Al = lds + 16384;
    char* Bh = lds + 32768;
    char* Bl = lds + 40960;
    const int t = threadIdx.x, lane = t & 63, w = t >> 6;
    const int s = w & 7, p = w >> 3;
    s_out = s; p_out = p;
    f32x4 z = {0.f, 0.f, 0.f, 0.f};
    acc = z;

    const int ar = t >> 4, ac = (t & 15) << 3;
    const int br = t >> 5, bc = (t & 31) << 2;
    const int asb = (ar * 256 + ac * 2) ^ ((ar & 15) << 4);
    const int bsb = (br * 256 + bc * 2) ^ ((br & 15) << 4);
    const float* Ap = Af + (size_t)(row0 + ar) * lda + ac;
    const unsigned short* Bhp = BThi + (size_t)(col0 + br) * ldk + bc;
    const unsigned short* Blp = BTlo + (size_t)(col0 + br) * ldk + bc;

    const int frow = s >> 1, fcol = s & 1;
    const int arow = frow * 16 + (lane & 15);
    const int colr = fcol * 16 + (lane & 15);
    const int ab0 = arow * 256, bb0 = colr * 256;
    const int axor = (arow & 15) << 4, bxor = (colr & 15) << 4;
    const int kwin = p * 128 + ((lane >> 4) << 4);

    float4 af0a = *(const float4*)(Ap),       af0b = *(const float4*)(Ap + 4);
    float4 af1a = *(const float4*)(Ap + 128), af1b = *(const float4*)(Ap + 132);
    uint2 bh0 = *(const uint2*)(Bhp),       bl0 = *(const uint2*)(Blp);
    uint2 bh1 = *(const uint2*)(Bhp + 128), bl1 = *(const uint2*)(Blp + 128);

    for (int k0 = 0; k0 < K; k0 += 128) {
        unsigned short h[8], l[8];
        const float vv[8] = {af0a.x, af0a.y, af0a.z, af0a.w,
                             af0b.x, af0b.y, af0b.z, af0b.w};
#pragma unroll
        for (int i = 0; i < 8; ++i) split2(vv[i], h[i], l[i]);
        uint4 awh = make_uint4((unsigned)h[0] | ((unsigned)h[1] << 16),
                               (unsigned)h[2] | ((unsigned)h[3] << 16),
                               (unsigned)h[4] | ((unsigned)h[5] << 16),
                               (unsigned)h[6] | ((unsigned)h[7] << 16));
        uint4 awl = make_uint4((unsigned)l[0] | ((unsigned)l[1] << 16),
                               (unsigned)l[2] | ((unsigned)l[3] << 16),
                               (unsigned)l[4] | ((unsigned)l[5] << 16),
                               (unsigned)l[6] | ((unsigned)l[7] << 16));
        const uint2 bwh = bh0, bwl = bl0;
        __syncthreads();
        *(uint4*)(Ah + asb) = awh;
        *(uint4*)(Al + asb) = awl;
        *(uint2*)(Bh + bsb) = bwh;
        *(uint2*)(Bl + bsb) = bwl;
        af0a = af1a; af0b = af1b;
        bh0 = bh1; bl0 = bl1;
        if (k0 + 256 < K) {
            af1a = *(const float4*)(Ap + k0 + 256);
            af1b = *(const float4*)(Ap + k0 + 260);
            bh1 = *(const uint2*)(Bhp + k0 + 256);
            bl1 = *(const uint2*)(Blp + k0 + 256);
        }
        __syncthreads();
#pragma unroll
        for (int ks = 0; ks < 2; ++ks) {
            const int kb = kwin + ks * 64;
            short8 bh = *(const short8*)(Bh + ((bb0 + kb) ^ bxor));
            short8 bl = *(const short8*)(Bl + ((bb0 + kb) ^ bxor));
            short8 ah = *(const short8*)(Ah + ((ab0 + kb) ^ axor));
            short8 al = *(const short8*)(Al + ((ab0 + kb) ^ axor));
            acc = __builtin_amdgcn_mfma_f32_16x16x32_bf16(ah, bh, acc, 0, 0, 0);
            acc = __builtin_amdgcn_mfma_f32_16x16x32_bf16(al, bh, acc, 0, 0, 0);
            acc = __builtin_amdgcn_mfma_f32_16x16x32_bf16(ah, bl, acc, 0, 0, 0);
        }
    }
}

// ---------------------------------------------------------------------------
// p1 tile: 64x32, K=2048 in 16 chunks of 128; A (16KB) + B (8KB) hi/lo images
// staged via global_load_lds. 8 fragments x 2-way K-split. LDS 48 KB.
// ---------------------------------------------------------------------------
__device__ __forceinline__ void tile64_img(
    const char* __restrict__ Ahi, const char* __restrict__ Alo,   // +16384/chunk
    const char* __restrict__ Bhi, const char* __restrict__ Blo,   // +8192/chunk
    char* lds, f32x4& acc, int& s_out, int& p_out)
{
    char* Ah = lds;
    char* Al = lds + 16384;
    char* Bh = lds + 32768;
    char* Bl = lds + 40960;
    const int t = threadIdx.x, lane = t & 63, w = t >> 6;
    const int s = w & 7, p = w >> 3;
    s_out = s; p_out = p;
    f32x4 z = {0.f, 0.f, 0.f, 0.f};
    acc = z;

    const int frow = s >> 1, fcol = s & 1;
    const int arow = frow * 16 + (lane & 15);
    const int colr = fcol * 16 + (lane & 15);
    const int ab0 = arow * 256, bb0 = colr * 256;
    const int axor = (arow & 15) << 4, bxor = (colr & 15) << 4;
    const int kwin = p * 128 + ((lane >> 4) << 4);
    const int t16 = t * 16;

    for (int kc = 0; kc < 16; ++kc) {
        __syncthreads();                            // buffer free (prior reads done)
        gload16(Ahi + ((size_t)kc << 14) + t16, Ah + (w << 10));
        gload16(Alo + ((size_t)kc << 14) + t16, Al + (w << 10));
        if (w < 8) gload16(Bhi + ((size_t)kc << 13) + t16, Bh + (w << 10));
        else       gload16(Blo + ((size_t)kc << 13) + t16 - 8192, Bl + ((w - 8) << 10));
        __syncthreads();                            // DMA drained -> LDS ready
#pragma unroll
        for (int ks = 0; ks < 2; ++ks) {
            const int kb = kwin + ks * 64;
            short8 bh = *(const short8*)(Bh + ((bb0 + kb) ^ bxor));
            short8 bl = *(const short8*)(Bl + ((bb0 + kb) ^ bxor));
            short8 ah = *(const short8*)(Ah + ((ab0 + kb) ^ axor));
            short8 al = *(const short8*)(Al + ((ab0 + kb) ^ axor));
            acc = __builtin_amdgcn_mfma_f32_16x16x32_bf16(ah, bh, acc, 0, 0, 0);
            acc = __builtin_amdgcn_mfma_f32_16x16x32_bf16(al, bh, acc, 0, 0, 0);
            acc = __builtin_amdgcn_mfma_f32_16x16x32_bf16(ah, bl, acc, 0, 0, 0);
        }
    }
}

// ---------------------------------------------------------------------------
// p2 tile: 32x32, K=2048 in 16 chunks; A (8KB half-image, stride 16384/chunk)
// + B (8KB, stride 8192/chunk) via global_load_lds. 4 frags x 4-way K-split.
// LDS 32 KB.
// ---------------------------------------------------------------------------
__device__ __forceinline__ void tile32_img(
    const char* __restrict__ Ahi, const char* __restrict__ Alo,
    const char* __restrict__ Bhi, const char* __restrict__ Blo,
    char* lds, f32x4& acc, int& s_out, int& p_out)
{
    char* Ah = lds;
    char* Al = lds + 8192;
    char* Bh = lds + 16384;
    char* Bl = lds + 24576;
    const int t = threadIdx.x, lane = t & 63, w = t >> 6;
    const int s = w & 3, p = w >> 2;
    s_out = s; p_out = p;
    f32x4 z = {0.f, 0.f, 0.f, 0.f};
    acc = z;

    const int frow = s >> 1, fcol = s & 1;
    const int arow = frow * 16 + (lane & 15);
    const int colr = fcol * 16 + (lane & 15);
    const int ab0 = arow * 256, bb0 = colr * 256;
    const int axor = (arow & 15) << 4, bxor = (colr & 15) << 4;
    const int kwin = p * 64 + ((lane >> 4) << 4);
    const int t16 = t * 16;

    for (int kc = 0; kc < 16; ++kc) {
        __syncthreads();
        if (w < 8) {
            gload16(Ahi + ((size_t)kc << 14) + t16, Ah + (w << 10));
            gload16(Bhi + ((size_t)kc << 13) + t16, Bh + (w << 10));
        } else {
            gload16(Alo + ((size_t)kc << 14) + t16 - 8192, Al + ((w - 8) << 10));
            gload16(Blo + ((size_t)kc << 13) + t16 - 8192, Bl + ((w - 8) << 10));
        }
        __syncthreads();
        const int kb = kwin;
        short8 bh = *(const short8*)(Bh + ((bb0 + kb) ^ bxor));
        short8 bl = *(const short8*)(Bl + ((bb0 + kb) ^ bxor));
        short8 ah = *(const short8*)(Ah + ((ab0 + kb) ^ axor));
        short8 al = *(const short8*)(Al + ((ab0 + kb) ^ axor));
        acc = __builtin_amdgcn_mfma_f32_16x16x32_bf16(ah, bh, acc, 0, 0, 0);
        acc = __builtin_amdgcn_mfma_f32_16x16x32_bf16(al, bh, acc, 0, 0, 0);
        acc = __builtin_amdgcn_mfma_f32_16x16x32_bf16(ah, bl, acc, 0, 0, 0);
    }
}

// ---------------------------------------------------------------------------
// Prep kernels
// ---------------------------------------------------------------------------
__global__ void k_init(int* active, int* cnt, float* scal,
                       float* margS, float* drift, int* fresh)
{
    int i = blockIdx.x * blockDim.x + threadIdx.x;
    if (i < 2 * BN) {
        active[i] = 1;
        margS[i] = 3.4e38f;
        drift[i] = 0.f;
        fresh[i] = 1;
    }
    if (i < 16) cnt[i] = 64;
    if (i < 8) scal[i] = 0.f;
}

__global__ __launch_bounds__(256) void k_colsum_wh(const float* __restrict__ RH,
                                                   const float* __restrict__ MH,
                                                   float* __restrict__ part)
{
    const int colTile = blockIdx.x >> 3, rs = blockIdx.x & 7;
    const int col = colTile * 64 + (threadIdx.x & 63);
    const int rq = threadIdx.x >> 6;
    const int r0 = rs * 256;
    float s = 0.f;
    for (int i = r0 + rq; i < r0 + 256; i += 4)
        s += fabsf(RH[(size_t)i * HDm + col] * MH[(size_t)i * HDm + col]);
    __shared__ float red[4][64];
    red[rq][threadIdx.x & 63] = s;
    __syncthreads();
    if (threadIdx.x < 64)
        part[(size_t)rs * HDm + col] = red[0][threadIdx.x] + red[1][threadIdx.x] +
                                       red[2][threadIdx.x] + red[3][threadIdx.x];
}

__global__ __launch_bounds__(256) void k_colsum_whl(const float* __restrict__ RHL,
                                                    const float* __restrict__ MHL,
                                                    float* __restrict__ part)
{
    const int colTile = blockIdx.x >> 3, rs = blockIdx.x & 7;
    const int col = colTile * 64 + (threadIdx.x & 63);
    const int rq = threadIdx.x >> 6;
    const int r0 = rs * 256;
    float s = 0.f;
    if (col < LD) {
        for (int i = r0 + rq; i < r0 + 256; i += 4)
            s += fabsf(RHL[(size_t)i * LD + col] * MHL[(size_t)i * LD + col]);
    }
    __shared__ float red[4][64];
    red[rq][threadIdx.x & 63] = s;
    __syncthreads();
    if (threadIdx.x < 64)
        part[(size_t)rs * 1024 + col] = red[0][threadIdx.x] + red[1][threadIdx.x] +
                                        red[2][threadIdx.x] + red[3][threadIdx.x];
}

__global__ __launch_bounds__(1024) void k_scalars(const float* __restrict__ part_wh,
                                                  const float* __restrict__ part_whl,
                                                  float* scal)
{
    float m1 = 0.f, m2 = 0.f;
    for (int c = threadIdx.x; c < HDm; c += 1024) {
        float s = 0.f;
#pragma unroll
        for (int k = 0; k < 8; ++k) s += part_wh[(size_t)k * HDm + c];
        m1 = fmaxf(m1, s);
    }
    {
        const int c = threadIdx.x;
        if (c < 1024) {
            float s = 0.f;
#pragma unroll
            for (int k = 0; k < 8; ++k) s += part_whl[(size_t)k * 1024 + c];
            m2 = fmaxf(m2, s);
        }
    }
#pragma unroll
    for (int off = 1; off < 64; off <<= 1) {
        m1 = fmaxf(m1, __shfl_xor(m1, off));
        m2 = fmaxf(m2, __shfl_xor(m2, off));
    }
    __shared__ float r1[16], r2[16];
    if ((threadIdx.x & 63) == 0) { r1[threadIdx.x >> 6] = m1; r2[threadIdx.x >> 6] = m2; }
    __syncthreads();
    if (threadIdx.x == 0) {
        float a = 0.f, b = 0.f;
#pragma unroll
        for (int i = 0; i < 16; ++i) { a = fmaxf(a, r1[i]); b = fmaxf(b, r2[i]); }
        scal[2] = 0.95f / fmaxf(a, 1e-8f);
        scal[3] = b * 19.f;
    }
}

// Linear transposed split (used for W_IH feeding the drive GEMM)
__global__ __launch_bounds__(256) void k_wsplit(
    const float* __restrict__ R, const float* __restrict__ M,
    unsigned short* __restrict__ Ohi, unsigned short* __restrict__ Olo,
    int NR, int NC, int NCp, const float* __restrict__ scal, int scidx)
{
    __shared__ float T[64][65];
    const int nct = NCp >> 6;
    const int c0 = (blockIdx.x % nct) << 6;
    const int r0 = (blockIdx.x / nct) << 6;
    const float s = (scidx >= 0) ? scal[scidx] : 1.f;
    const int t = threadIdx.x;
    const int ir = t >> 2, ics = (t & 3) << 4;
#pragma unroll
    for (int i = 0; i < 16; ++i) {
        const int c = c0 + ics + i;
        float v = 0.f;
        if (c < NC) {
            const size_t idx = (size_t)(r0 + ir) * NC + c;
            v = R[idx] * M[idx] * s;
        }
        T[ir][ics + i] = v;
    }
    __syncthreads();
    const int oc = t >> 2, ors = (t & 3) << 4;
    unsigned short hb[16], lb[16];
#pragma unroll
    for (int i = 0; i < 16; ++i) split2(T[ors + i][oc], hb[i], lb[i]);
    const size_t base = (size_t)(c0 + oc) * NR + r0 + ors;
    uint4 v;
    v.x = hb[0] | ((unsigned)hb[1] << 16);  v.y = hb[2] | ((unsigned)hb[3] << 16);
    v.z = hb[4] | ((unsigned)hb[5] << 16);  v.w = hb[6] | ((unsigned)hb[7] << 16);
    *(uint4*)(Ohi + base) = v;
    v.x = hb[8] | ((unsigned)hb[9] << 16);  v.y = hb[10] | ((unsigned)hb[11] << 16);
    v.z = hb[12] | ((unsigned)hb[13] << 16); v.w = hb[14] | ((unsigned)hb[15] << 16);
    *(uint4*)(Ohi + base + 8) = v;
    v.x = lb[0] | ((unsigned)lb[1] << 16);  v.y = lb[2] | ((unsigned)lb[3] << 16);
    v.z = lb[4] | ((unsigned)lb[5] << 16);  v.w = lb[6] | ((unsigned)lb[7] << 16);
    *(uint4*)(Olo + base) = v;
    v.x = lb[8] | ((unsigned)lb[9] << 16);  v.y = lb[10] | ((unsigned)lb[11] << 16);
    v.z = lb[12] | ((unsigned)lb[13] << 16); v.w = lb[14] | ((unsigned)lb[15] << 16);
    *(uint4*)(Olo + base + 8) = v;
}

// Image-format transposed split: block = (tile32, kchunk); writes the exact
// 8 KB swizzled LDS image global_load_lds will stream.
__global__ __launch_bounds__(256) void k_wsplit_img(
    const float* __restrict__ R, const float* __restrict__ M,
    char* __restrict__ imghi, char* __restrict__ imglo,
    int NC, int nkc, const float* __restrict__ scal, int scidx)
{
    const int ct = blockIdx.x / nkc, kc = blockIdx.x % nkc;
    const float s = (scidx >= 0) ? scal[scidx] : 1.f;
    char* hi = imghi + ((size_t)(ct * nkc + kc) << 13);
    char* lo = imglo + ((size_t)(ct * nkc + kc) << 13);
#pragma unroll
    for (int i = 0; i < 16; ++i) {
        const int idx = i * 256 + threadIdx.x;
        const int br = idx & 31, bc = idx >> 5;
        const int c = ct * 32 + br;          // weight column (output unit)
        const int k = kc * 128 + bc;         // weight row (contraction index)
        float v = 0.f;
        if (c < NC) { const size_t a = (size_t)k * NC + c; v = R[a] * M[a] * s; }
        unsigned short h, l;
        split2(v, h, l);
        const int byte = (br * 256 + bc * 2) ^ ((br & 15) << 4);
        *(unsigned short*)(hi + byte) = h;
        *(unsigned short*)(lo + byte) = l;
    }
}

// drive = x @ W_IH + BH   (512 blocks = 8 x 64 tiles of 64x32, K=1024)
__global__ __launch_bounds__(1024, 8) void k_drive_mfma(
    const float* __restrict__ x,
    const unsigned short* __restrict__ WIHThi, const unsigned short* __restrict__ WIHTlo,
    const float* __restrict__ BH, float* __restrict__ drive)
{
    __shared__ char lds[49152];
    f32x4 acc;
    int s, p;
    const int row0 = (blockIdx.x >> 6) * 64, col0 = (blockIdx.x & 63) * 32;
    tile64_drive(x, ID, row0, WIHThi, WIHTlo, ID, col0, ID, lds, acc, s, p);
    const int lane = threadIdx.x & 63;
    __syncthreads();
    f32x4* red = (f32x4*)lds;
    if (p == 1) red[s * 64 + lane] = acc;
    __syncthreads();
    if (p == 0) {
        f32x4 o = red[s * 64 + lane];
        acc += o;
        const int frow = s >> 1, fcol = s & 1;
        const int gc = col0 + fcol * 16 + (lane & 15);
        const int gr0 = row0 + frow * 16 + ((lane >> 4) << 2);
        const float bh = BH[gc];
#pragma unroll
        for (int r = 0; r < 4; ++r)
            drive[(size_t)(gr0 + r) * HDm + gc] = acc[r] + bh;
    }
}

// ---------------------------------------------------------------------------
// k_p1(t): finalize(t-1) from parity-(t-1) partials, then
// Hn = select(active, LeakyReLU(Hs@W_H + drive), Hs) + dH partials.
// H stored in image format (hi/lo char arrays). Grid 512 = 8 rt x 64 ct.
// ---------------------------------------------------------------------------
__global__ __launch_bounds__(1024, 8) void k_p1(
    const char* __restrict__ WHhi, const char* __restrict__ WHlo,
    const float* __restrict__ drive,
    char* __restrict__ HAhi, char* __restrict__ HAlo,
    char* __restrict__ HBhi, char* __restrict__ HBlo,
    const float* __restrict__ logits, float* __restrict__ out,
    int* __restrict__ active, int* __restrict__ cnt, const float* __restrict__ scal,
    float* __restrict__ dhp, const float* __restrict__ m1p, const float* __restrict__ m2p,
    float* __restrict__ margS, float* __restrict__ drift, const int* __restrict__ fresh,
    int t)
{
    __shared__ char lds[49152];
    __shared__ int sact[64], snew[64];
    __shared__ int s_cnt;
    const int pp = (t - 1) & 1, pc = t & 1;
    {   // frozen early-exit gate (written by p1(t-1) only)
        const int* cp = cnt + pp * 8;
        int sum = 0;
#pragma unroll
        for (int i = 0; i < 8; ++i) sum += cp[i];
        if (sum == 0) return;
    }
    const int bid = blockIdx.x, tid = threadIdx.x;
    const int rt = bid >> 6, row0m = rt << 6, col0 = (bid & 63) * 32;
    const int* actP = active + pp * BN;
    int* actC = active + pc * BN;
    const char* Hshi = (t & 1) ? HAhi : HBhi;
    const char* Hslo = (t & 1) ? HAlo : HBlo;
    char* Hnhi = (t & 1) ? HBhi : HAhi;
    char* Hnlo = (t & 1) ? HBlo : HAlo;
    const float* dhpP = dhp + (size_t)pp * BN * 64;
    float* dhpC = dhp + (size_t)pc * BN * 64;
    const float* margSP = margS + pp * BN;
    float* margSC = margS + pc * BN;
    const float* driftP = drift + pp * BN;
    float* driftC = drift + pc * BN;
    const int* freshP = fresh + pp * BN;

    // ---- finalize(t-1): certification from frozen partials ----
    if (t > 1) {
        const float gamma2 = 2.f * scal[3];
        const int rl = tid >> 4, j = tid & 15;
        const int r = row0m + rl;
        const int act = actP[r];
        const int fr = freshP[r];
        float dh = fmaxf(fmaxf(dhpP[(size_t)r * 64 + j],      dhpP[(size_t)r * 64 + 16 + j]),
                         fmaxf(dhpP[(size_t)r * 64 + 32 + j], dhpP[(size_t)r * 64 + 48 + j]));
        float M1 = m1p[(size_t)r * 32 + j], M2 = m2p[(size_t)r * 32 + j];
        {
            float o1 = m1p[(size_t)r * 32 + 16 + j], o2 = m2p[(size_t)r * 32 + 16 + j];
            if (o1 > M1) { M2 = fmaxf(M1, o2); M1 = o1; }
            else M2 = fmaxf(M2, o1);
        }
#pragma unroll
        for (int off = 1; off < 16; off <<= 1) {
            dh = fmaxf(dh, __shfl_xor(dh, off));
            float o1 = __shfl_xor(M1, off), o2 = __shfl_xor(M2, off);
            if (o1 > M1) { M2 = fmaxf(M1, o2); M1 = o1; }
            else M2 = fmaxf(M2, o1);
        }
        if (j == 0) {
            const float marg = M1 - M2;
            int nw = fr && act && (marg > gamma2 * dh);
            snew[rl] = nw;
            sact[rl] = act && !nw;
            margSC[r] = fr ? marg : margSP[r];
            driftC[r] = fr ? 0.f : (driftP[r] + dh);
        }
    } else if (tid < 64) {
        sact[tid] = 1; snew[tid] = 0;
    }
    __syncthreads();
    if (tid < 64) {
        unsigned long long b = __ballot(sact[tid] != 0);
        actC[row0m + tid] = sact[tid];
        if (tid == 0) {
            s_cnt = __popcll(b);
            (cnt + pc * 8)[rt] = s_cnt;
        }
    }
    if (t > 1 && (bid & 63) == 0) {
        for (int rl2 = 0; rl2 < 64; ++rl2) {
            if (snew[rl2]) {
                const float* lr = logits + (size_t)(row0m + rl2) * LD;
                float* orow = out + (size_t)(row0m + rl2) * LD;
                for (int jj = tid; jj < LD; jj += 1024) orow[jj] = lr[jj];
            }
        }
    }
    __syncthreads();
    if (s_cnt == 0) return;

    // ---- P1 GEMM (image DMA staging) ----
    f32x4 acc;
    int s, p;
    tile64_img(Hshi + ((size_t)(rt * 16) << 14), Hslo + ((size_t)(rt * 16) << 14),
               WHhi + ((size_t)((bid & 63) * 16) << 13), WHlo + ((size_t)((bid & 63) * 16) << 13),
               lds, acc, s, p);
    const int lane = tid & 63;
    __syncthreads();
    f32x4* red = (f32x4*)lds;
    if (p == 1) red[s * 64 + lane] = acc;
    __syncthreads();
    float (*sdh)[2] = (float(*)[2])(lds + 16384);
    if (p == 0) {
        f32x4 o = red[s * 64 + lane];
        acc += o;
        const int frow = s >> 1, fcol = s & 1;
        const int gc = col0 + fcol * 16 + (lane & 15);
        const int gr0 = row0m + frow * 16 + ((lane >> 4) << 2);
        float dh4[4];
#pragma unroll
        for (int r = 0; r < 4; ++r) {
            const int gr = gr0 + r;
            const size_t ia = himg_off(gr, gc);
            const unsigned short oh = *(const unsigned short*)(Hshi + ia);
            const unsigned short ol = *(const unsigned short*)(Hslo + ia);
            const float old = bf2f(oh) + bf2f(ol);
            const int a = sact[gr - row0m];
            unsigned short nh, nl;
            if (a) {
                const float pre = acc[r] + drive[(size_t)gr * HDm + gc];
                const float av = pre >= 0.f ? pre : ALPHAc * pre;
                split2(av, nh, nl);
            } else { nh = oh; nl = ol; }
            *(unsigned short*)(Hnhi + ia) = nh;
            *(unsigned short*)(Hnlo + ia) = nl;
            dh4[r] = fabsf((bf2f(nh) + bf2f(nl)) - old);   // exactly 0 for frozen rows
        }
#pragma unroll
        for (int off = 1; off < 16; off <<= 1)
#pragma unroll
            for (int r = 0; r < 4; ++r)
                dh4[r] = fmaxf(dh4[r], __shfl_xor(dh4[r], off));
        if ((lane & 15) == 0) {
            const int rl0 = frow * 16 + ((lane >> 4) << 2);
#pragma unroll
            for (int r = 0; r < 4; ++r) sdh[rl0 + r][fcol] = dh4[r];
        }
    }
    __syncthreads();
    if (tid < 64) {
        float d = fmaxf(sdh[tid][0], sdh[tid][1]);
        dhpC[(size_t)(row0m + tid) * 64 + (bid & 63)] = d;
    }
}

// ---------------------------------------------------------------------------
// k_p2(t): Lipschitz gate, then logits = Hn @ W_HL + BL + top2 partials.
// Grid 512 = 16 row-tiles(32) x 32 col-tiles(32).
// ---------------------------------------------------------------------------
__global__ __launch_bounds__(1024, 8) void k_p2(
    const char* __restrict__ WLhi, const char* __restrict__ WLlo,
    const float* __restrict__ BL,
    const char* __restrict__ HAhi, const char* __restrict__ HAlo,
    const char* __restrict__ HBhi, const char* __restrict__ HBlo,
    float* __restrict__ logits, const int* __restrict__ active, const int* __restrict__ cnt,
    float* __restrict__ m1p, float* __restrict__ m2p, const float* __restrict__ scal,
    const float* __restrict__ dhp, const float* __restrict__ margS,
    const float* __restrict__ drift, int* __restrict__ fresh, int t)
{
    __shared__ char lds[33280];
    __shared__ int sposs[32];
    __shared__ int s_go;
    const int pc = t & 1;
    {
        const int* cp = cnt + pc * 8;
        int sum = 0;
#pragma unroll
        for (int i = 0; i < 8; ++i) sum += cp[i];
        if (sum == 0) return;
    }
    const int bid = blockIdx.x, tid = threadIdx.x;
    const char* Hnhi = (t & 1) ? HBhi : HAhi;
    const char* Hnlo = (t & 1) ? HBlo : HAlo;
    const int* actC = active + pc * BN;
    const float* dhpC = dhp + (size_t)pc * BN * 64;
    const float* margSc = margS + pc * BN;
    const float* driftc = drift + pc * BN;
    int* freshC = fresh + pc * BN;
    const int row0 = (bid >> 5) * 32, col0 = (bid & 31) * 32;

    // ---- Lipschitz impossibility gate ----
    {
        const int rr = tid >> 5, j = tid & 31;
        const int r = row0 + rr;
        float d = fmaxf(dhpC[(size_t)r * 64 + j], dhpC[(size_t)r * 64 + 32 + j]);
#pragma unroll
        for (int off = 1; off < 32; off <<= 1) d = fmaxf(d, __shfl_xor(d, off));
        if (j == 0) {
            const int act = actC[r];
            int poss;
            if (t == TMAXc) poss = act;
            else {
                const float whl = scal[3] * (1.f / 19.f);
                poss = act && (margSc[r] + 2.f * whl * (driftc[r] + d) >
                               0.99f * 38.f * whl * d);
            }
            sposs[rr] = poss;
        }
    }
    __syncthreads();
    if (tid < 64) {
        int v = (tid < 32) ? sposs[tid] : 0;
        unsigned long long b = __ballot(v != 0);
        if (tid == 0) s_go = (b != 0ull);
    }
    __syncthreads();
    if (tid < 32) freshC[row0 + tid] = s_go;
    if (!s_go) return;

    // ---- P2 GEMM (image DMA staging) ----
    const int rt2 = bid >> 5;
    const char* Ahi = Hnhi + ((size_t)((rt2 >> 1) * 16) << 14) + ((rt2 & 1) << 13);
    const char* Alo = Hnlo + ((size_t)((rt2 >> 1) * 16) << 14) + ((rt2 & 1) << 13);
    f32x4 acc;
    int s, p;
    tile32_img(Ahi, Alo,
               WLhi + ((size_t)((bid & 31) * 16) << 13), WLlo + ((size_t)((bid & 31) * 16) << 13),
               lds, acc, s, p);
    const int lane = tid & 63;
    __syncthreads();
    f32x4* red = (f32x4*)lds;                       // 3 x 4 x 64 x 16B = 12 KB
    if (p > 0) red[(p - 1) * 256 + s * 64 + lane] = acc;
    __syncthreads();
    float (*st1)[2] = (float(*)[2])(lds + 12288);
    float (*st2)[2] = (float(*)[2])(lds + 12544);
    if (p == 0) {
#pragma unroll
        for (int q = 0; q < 3; ++q) {
            f32x4 o = red[q * 256 + s * 64 + lane];
            acc += o;
        }
        const int frow = s >> 1, fcol = s & 1;
        const int gc = col0 + fcol * 16 + (lane & 15);
        const int gr0 = row0 + frow * 16 + ((lane >> 4) << 2);
        const bool okc = gc < LD;
        const float blv = okc ? BL[gc] : 0.f;
        float m1a[4], m2a[4];
#pragma unroll
        for (int r = 0; r < 4; ++r) {
            const float v = acc[r] + blv;
            if (okc) logits[(size_t)(gr0 + r) * LD + gc] = v;
            m1a[r] = okc ? v : -3.4e38f;
            m2a[r] = -3.4e38f;
        }
#pragma unroll
        for (int off = 1; off < 16; off <<= 1) {
#pragma unroll
            for (int r = 0; r < 4; ++r) {
                float o1 = __shfl_xor(m1a[r], off);
                float o2 = __shfl_xor(m2a[r], off);
                if (o1 > m1a[r]) { m2a[r] = fmaxf(m1a[r], o2); m1a[r] = o1; }
                else m2a[r] = fmaxf(m2a[r], o1);
            }
        }
        if ((lane & 15) == 0) {
            const int rl0 = frow * 16 + ((lane >> 4) << 2);
#pragma unroll
            for (int r = 0; r < 4; ++r) {
                st1[rl0 + r][fcol] = m1a[r];
                st2[rl0 + r][fcol] = m2a[r];
            }
        }
    }
    __syncthreads();
    if (tid < 32) {
        float M1 = st1[tid][0], M2 = st2[tid][0];
        {
            float o1 = st1[tid][1], o2 = st2[tid][1];
            if (o1 > M1) { M2 = fmaxf(M1, o2); M1 = o1; }
            else M2 = fmaxf(M2, o1);
        }
        m1p[(size_t)(row0 + tid) * 32 + (bid & 31)] = M1;
        m2p[(size_t)(row0 + tid) * 32 + (bid & 31)] = M2;
    }
}

// rows never finalized-certified take the last-step logits
__global__ __launch_bounds__(1024) void k_tail(
    const float* __restrict__ logits, const int* __restrict__ active,
    float* __restrict__ out)
{
    const int row0 = blockIdx.x * 64;
    for (int rl = 0; rl < 64; ++rl) {
        const int r = row0 + rl;
        if (active[r] && active[BN + r]) {
            const float* lr = logits + (size_t)r * LD;
            float* orow = out + (size_t)r * LD;
            for (int jj = threadIdx.x; jj < LD; jj += 1024) orow[jj] = lr[jj];
        }
    }
}

// ---------------------------------------------------------------------------
extern "C" void kernel_launch(void* const* d_in, const int* in_sizes, int n_in,
                              void* d_out, int out_size, void* d_ws, size_t ws_size,
                              hipStream_t stream)
{
    const float* x   = (const float*)d_in[0];
    const float* RIH = (const float*)d_in[1];
    const float* RH  = (const float*)d_in[2];
    const float* RHL = (const float*)d_in[3];
    const float* BH  = (const float*)d_in[4];
    const float* BL  = (const float*)d_in[5];
    const float* MIH = (const float*)d_in[6];
    const float* MH  = (const float*)d_in[7];
    const float* MHL = (const float*)d_in[8];
    float* out = (float*)d_out;
    char* w = (char*)d_ws;

    char* WHhi = w;                                               //  8 MB (W_H img: 64ct x 16kc x 8KB)
    char* WHlo = w + 8388608;                                     //  8 MB
    char* WXhi = w + 16777216;                                    //  4 MB (W_IH linear, then W_HL img)
    char* WXlo = w + 20971520;                                    //  4 MB
    float* drive = (float*)(w + 25165824);                        //  4 MB
    char* HAhi = w + 29360128;                                    //  2 MB (H img: 8rt x 16kc x 16KB)
    char* HAlo = w + 31457280;                                    //  2 MB
    char* HBhi = w + 33554432;                                    //  2 MB
    char* HBlo = w + 35651584;                                    //  2 MB
    float* logits = (float*)(w + 37748736);                       //  2 MB
    float* scal   = (float*)(w + 39796736);
    int*   active = (int*)(w + 39796800);
    int*   cnt    = (int*)(w + 39800896);
    float* dhp    = (float*)(w + 39800960);                       //  256 KB
    float* m1p    = (float*)(w + 40063104);                       //  64 KB
    float* m2p    = (float*)(w + 40128640);                       //  64 KB
    float* margS  = (float*)(w + 40194176);
    float* drift  = (float*)(w + 40198272);
    int*   fresh  = (int*)(w + 40202368);

    k_init<<<4, 256, 0, stream>>>(active, cnt, scal, margS, drift, fresh);
    k_colsum_wh<<<256, 256, 0, stream>>>(RH, MH, dhp);            // dhp reused as part_wh
    k_colsum_whl<<<128, 256, 0, stream>>>(RHL, MHL, m1p);         // m1p reused as part_whl
    k_scalars<<<1, 1024, 0, stream>>>(dhp, m1p, scal);
    k_wsplit<<<512, 256, 0, stream>>>(RIH, MIH, (unsigned short*)WXhi,
                                      (unsigned short*)WXlo, ID, HDm, HDm, scal, -1);
    k_drive_mfma<<<512, 1024, 0, stream>>>(x, (const unsigned short*)WXhi,
                                           (const unsigned short*)WXlo, BH, drive);
    k_wsplit_img<<<1024, 256, 0, stream>>>(RH, MH, WHhi, WHlo, HDm, 16, scal, 2);
    k_wsplit_img<<<512, 256, 0, stream>>>(RHL, MHL, WXhi, WXlo, LD, 16, scal, -1);
    (void)hipMemsetAsync(HAhi, 0, 4194304, stream);   // zeros HAhi + HAlo (contiguous)

    for (int t = 1; t <= TMAXc; ++t) {
        k_p1<<<512, 1024, 0, stream>>>(WHhi, WHlo, drive, HAhi, HAlo, HBhi, HBlo,
                                       logits, out, active, cnt, scal, dhp, m1p, m2p,
                                       margS, drift, fresh, t);
        k_p2<<<512, 1024, 0, stream>>>(WXhi, WXlo, BL, HAhi, HAlo, HBhi, HBlo,
                                       logits, active, cnt, m1p, m2p, scal,
                                       dhp, margS, drift, fresh, t);
    }
    k_tail<<<8, 1024, 0, stream>>>(logits, active, out);
}